// Round 1
// baseline (5796.660 us; speedup 1.0000x reference)
//
#include <hip/hip_runtime.h>
#include <hip/hip_bf16.h>
#include <math.h>

typedef __hip_bfloat16 bf16;
using s16x8 = __attribute__((ext_vector_type(8))) short;
using f32x4 = __attribute__((ext_vector_type(4))) float;

#define RTOT 4096      // B*S rows
#define XLD  2112      // combined-input stride (K1 padded: 2052->2112)
#define NT1  2304      // GEMM1 padded N (2 nets x 1152, real 1028 each)
#define HLD  2176      // H stride (2 nets x 1088)
#define KH   1088      // GEMM2 K padded (1028->1088)
#define N2P  640       // GEMM2 padded N per net (514->640)
#define CLD  640       // c/t/fc/nc fp32 stride
#define KDP  576       // small-mlp K padded (514->576)
#define NDC  512       // d+s hidden padded (257+128=385 -> 512)
#define NDT  384       // d hidden padded (257 -> 384)
#define F2E  514
#define SP   512

__device__ __forceinline__ float gelu_ex(float x) {
    return 0.5f * x * (1.0f + erff(x * 0.70710678118654752f));
}
__device__ __forceinline__ float sigm(float x) { return 1.0f / (1.0f + expf(-x)); }
__device__ __forceinline__ float n2n(float x) {
    if (isnan(x)) return 0.0f;
    if (isinf(x)) return x > 0.0f ? 1e6f : -1e6f;
    return x;
}

// ---------------- bf16 MFMA GEMM: C[M,N] = A[M,K] * Bt[N,K]^T (+bias, epilogue) ----
// EPI: 0 = x+bias, 1 = tanh(x+bias), 2 = gelu(x+bias)
template<int EPI>
__global__ __launch_bounds__(256)
void gemm_bt(const bf16* __restrict__ A, int lda,
             const bf16* __restrict__ Bt, int ldb,
             float* __restrict__ C, int ldc,
             const float* __restrict__ bias, int ktiles)
{
    __shared__ __align__(16) short As[128 * 32];
    __shared__ __align__(16) short Bs[128 * 32];
    const int tid  = threadIdx.x;
    const int lane = tid & 63;
    const int wave = tid >> 6;
    const int l15  = lane & 15, kl = lane >> 4;
    const long mb = (long)blockIdx.x * 128;
    const long nb = (long)blockIdx.y * 128;
    const int wr = (wave >> 1) * 64;
    const int wc = (wave & 1) * 64;

    f32x4 acc[4][4] = {};

    // staging: 2 slots/thread per operand; slot s covers row=slot>>2, chunk=slot&3 (8 bf16)
    const int r0 = tid >> 2, c0 = tid & 3;
    const int r1 = r0 + 64;
    const int lc0 = c0 ^ ((r0 >> 1) & 3);   // XOR chunk swizzle (both write & read sides)
    const int lc1 = c0 ^ ((r1 >> 1) & 3);
    const bf16* Ap0 = A  + (mb + r0) * (long)lda + c0 * 8;
    const bf16* Ap1 = A  + (mb + r1) * (long)lda + c0 * 8;
    const bf16* Bp0 = Bt + (nb + r0) * (long)ldb + c0 * 8;
    const bf16* Bp1 = Bt + (nb + r1) * (long)ldb + c0 * 8;

    s16x8 va0 = *reinterpret_cast<const s16x8*>(Ap0);
    s16x8 va1 = *reinterpret_cast<const s16x8*>(Ap1);
    s16x8 vb0 = *reinterpret_cast<const s16x8*>(Bp0);
    s16x8 vb1 = *reinterpret_cast<const s16x8*>(Bp1);

    for (int kt = 0; kt < ktiles; ++kt) {
        __syncthreads();
        *reinterpret_cast<s16x8*>(&As[r0 * 32 + lc0 * 8]) = va0;
        *reinterpret_cast<s16x8*>(&As[r1 * 32 + lc1 * 8]) = va1;
        *reinterpret_cast<s16x8*>(&Bs[r0 * 32 + lc0 * 8]) = vb0;
        *reinterpret_cast<s16x8*>(&Bs[r1 * 32 + lc1 * 8]) = vb1;
        __syncthreads();
        if (kt + 1 < ktiles) {                     // prefetch next tile; hides under MFMAs
            const int ko = (kt + 1) * 32;
            va0 = *reinterpret_cast<const s16x8*>(Ap0 + ko);
            va1 = *reinterpret_cast<const s16x8*>(Ap1 + ko);
            vb0 = *reinterpret_cast<const s16x8*>(Bp0 + ko);
            vb1 = *reinterpret_cast<const s16x8*>(Bp1 + ko);
        }
        s16x8 af[4], bfr[4];
#pragma unroll
        for (int m = 0; m < 4; ++m) {
            int ar = wr + m * 16 + l15;
            af[m] = *reinterpret_cast<const s16x8*>(&As[ar * 32 + ((kl ^ ((ar >> 1) & 3)) * 8)]);
        }
#pragma unroll
        for (int n = 0; n < 4; ++n) {
            int br = wc + n * 16 + l15;
            bfr[n] = *reinterpret_cast<const s16x8*>(&Bs[br * 32 + ((kl ^ ((br >> 1) & 3)) * 8)]);
        }
#pragma unroll
        for (int m = 0; m < 4; ++m)
#pragma unroll
            for (int n = 0; n < 4; ++n)
                acc[m][n] = __builtin_amdgcn_mfma_f32_16x16x32_bf16(af[m], bfr[n], acc[m][n], 0, 0, 0);
    }

#pragma unroll
    for (int m = 0; m < 4; ++m) {
        const long grow0 = mb + wr + m * 16 + kl * 4;
#pragma unroll
        for (int n = 0; n < 4; ++n) {
            const long gcol = nb + wc + n * 16 + l15;
            const float bb = bias[gcol];
            f32x4 v = acc[m][n];
#pragma unroll
            for (int r = 0; r < 4; ++r) {
                float x = v[r] + bb;
                if (EPI == 1) x = tanhf(x);
                else if (EPI == 2) x = gelu_ex(x);
                C[(grow0 + r) * (long)ldc + gcol] = x;
            }
        }
    }
}

// ---------------- fp32 SGEMM (rfft/irfft tables): C[M,N] = A[M,K] * Bt[N,K]^T -------
__global__ __launch_bounds__(256)
void sgemm_bt(const float* __restrict__ A, int lda,
              const float* __restrict__ Bt, int ldb,
              float* __restrict__ C, int ldc, int ktiles)
{
    __shared__ float As[64][17];
    __shared__ float Bs[64][17];
    const int tid = threadIdx.x;
    const int tx = tid & 15, ty = tid >> 4;
    const long mb = (long)blockIdx.x * 64, nb = (long)blockIdx.y * 64;
    float acc[4][4] = {};
    for (int kt = 0; kt < ktiles; ++kt) {
#pragma unroll
        for (int e = 0; e < 4; ++e) {
            int idx = e * 256 + tid;
            int r = idx >> 4, k = idx & 15;
            As[r][k] = A[(mb + r) * (long)lda + kt * 16 + k];
            Bs[r][k] = Bt[(nb + r) * (long)ldb + kt * 16 + k];
        }
        __syncthreads();
#pragma unroll
        for (int kk = 0; kk < 16; ++kk) {
            float a[4], b[4];
#pragma unroll
            for (int i = 0; i < 4; ++i) a[i] = As[ty * 4 + i][kk];
#pragma unroll
            for (int j = 0; j < 4; ++j) b[j] = Bs[tx * 4 + j][kk];
#pragma unroll
            for (int i = 0; i < 4; ++i)
#pragma unroll
                for (int j = 0; j < 4; ++j) acc[i][j] = fmaf(a[i], b[j], acc[i][j]);
        }
        __syncthreads();
    }
#pragma unroll
    for (int i = 0; i < 4; ++i)
#pragma unroll
        for (int j = 0; j < 4; ++j)
            C[(mb + ty * 4 + i) * (long)ldc + nb + tx * 4 + j] = acc[i][j];
}

// ---------------- setup kernels ----------------
__global__ void build_tables(float* __restrict__ RT, float* __restrict__ IT)
{
    long idx = (long)blockIdx.x * 256 + threadIdx.x;
    const double W = 6.283185307179586476925286766559005768 / 512.0;
    if (idx < 640L * 512) {                  // RT[640][512]: rfft rows (re/im interleaved)
        int r = (int)(idx >> 9), n = (int)(idx & 511);
        float v = 0.f;
        if (r < F2E) {
            int bin = r >> 1;
            int m = (bin * n) & 511;
            double ang = W * m;
            v = (r & 1) ? (float)(-sin(ang)) : (float)cos(ang);
        }
        RT[idx] = v;
    } else {
        long j2 = idx - 640L * 512;          // IT[512][640]: irfft rows
        if (j2 < 512L * 640) {
            int n = (int)(j2 / 640), j = (int)(j2 % 640);
            float v = 0.f;
            if (j < F2E) {
                int bin = j >> 1;
                int m = (bin * n) & 511;
                double ang = W * m;
                bool edge = (bin == 0 || bin == 256);
                double ck = edge ? 1.0 : 2.0;
                if (j & 1) v = edge ? 0.f : (float)(-ck * sin(ang) / 512.0);
                else       v = (float)(ck * cos(ang) / 512.0);
            }
            IT[j2] = v;
        }
    }
}

__global__ void build_damp(float* damp, const float* __restrict__ fd)
{
    int i = blockIdx.x * 256 + threadIdx.x;
    if (i < F2E) damp[i] = fd[i < 257 ? i : i - 257];   // torch repeat(...,2) tiling quirk
}

// transpose fp32 [K,N] weights into bf16 [rows=ldn][cols=ldk], zero-padded, 2 segments
__global__ void wprep(bf16* __restrict__ dst, int ldk,
                      const float* s0, int K0, int N0, int r00,
                      const float* s1, int K1, int N1, int r01)
{
    int r = blockIdx.x;
    int k = blockIdx.y * 256 + threadIdx.x;
    if (k >= ldk) return;
    float v = 0.f;
    if (s0 && r >= r00 && r < r00 + N0 && k < K0) v = s0[(long)k * N0 + (r - r00)];
    if (s1 && r >= r01 && r < r01 + N1 && k < K1) v = s1[(long)k * N1 + (r - r01)];
    dst[(long)r * ldk + k] = __float2bfloat16(v);
}

__global__ void bias_fill(float* __restrict__ dst, int n,
                          const float* s0, int l0, int o0,
                          const float* s1, int l1, int o1)
{
    int i = blockIdx.x * 256 + threadIdx.x;
    if (i >= n) return;
    float v = 0.f;
    if (s0 && i >= o0 && i < o0 + l0) v = s0[i - o0];
    if (s1 && i >= o1 && i < o1 + l1) v = s1[i - o1];
    dst[i] = v;
}

__global__ void fill_xst(bf16* __restrict__ X, const float* __restrict__ srcp,
                         const float* __restrict__ tgtp)
{
    int row = blockIdx.x;
    int j = blockIdx.y * 256 + threadIdx.x;   // grid.y=2 -> j<512
    int b = row >> 9;
    X[(long)row * XLD + 1028 + j] = __float2bfloat16(srcp[b * 513 + j]);
    X[(long)row * XLD + 1540 + j] = __float2bfloat16(tgtp[b * 513 + j]);
}

__global__ void initconv(const float* __restrict__ cb, const float* __restrict__ tb,
                         bf16* __restrict__ X, bf16* __restrict__ Cb, bf16* __restrict__ Tb)
{
    int row = blockIdx.x;
    for (int j = threadIdx.x; j < F2E; j += 256) {
        float cv = cb[(long)row * CLD + j], tv = tb[(long)row * CLD + j];
        X[(long)row * XLD + j]        = __float2bfloat16(cv);
        X[(long)row * XLD + 514 + j]  = __float2bfloat16(tv);
        Cb[(long)row * KDP + j] = __float2bfloat16(n2n(cv));
        Tb[(long)row * KDP + j] = __float2bfloat16(n2n(tv));
    }
}

// ---------------- per-step kernels ----------------
__global__ __launch_bounds__(256)
void ln_gelu(const float* __restrict__ Y, bf16* __restrict__ H,
             const float* __restrict__ cg, const float* __restrict__ cbeta,
             const float* __restrict__ tg, const float* __restrict__ tbeta)
{
    __shared__ float red[8];
    const int row = blockIdx.x, net = blockIdx.y;
    const int tid = threadIdx.x, lane = tid & 63, wave = tid >> 6;
    const float* y = Y + (long)row * NT1 + net * 1152;
    bf16* h = H + (long)row * HLD + (long)net * KH;
    const float* g  = net ? tg : cg;
    const float* be = net ? tbeta : cbeta;
    float xv[5]; int cnt = 0;
    float s = 0.f;
    for (int j = tid; j < 1028; j += 256) { float v = y[j]; xv[cnt++] = v; s += v; }
    for (int o = 32; o > 0; o >>= 1) s += __shfl_down(s, o, 64);
    if (lane == 0) red[wave] = s;
    __syncthreads();
    float mean = (red[0] + red[1] + red[2] + red[3]) * (1.0f / 1028.0f);
    __syncthreads();
    float vs = 0.f;
    for (int i = 0; i < cnt; ++i) { float d = xv[i] - mean; vs += d * d; }
    for (int o = 32; o > 0; o >>= 1) vs += __shfl_down(vs, o, 64);
    if (lane == 0) red[wave] = vs;
    __syncthreads();
    float var = (red[0] + red[1] + red[2] + red[3]) * (1.0f / 1028.0f);
    float rs = rsqrtf(var + 1e-5f);
    cnt = 0;
    for (int j = tid; j < 1028; j += 256) {
        float v = (xv[cnt++] - mean) * rs * g[j] + be[j];
        h[j] = __float2bfloat16(gelu_ex(v));
    }
}

__global__ __launch_bounds__(256)
void heads(const float* __restrict__ Hdc, const float* __restrict__ Hdt,
           const float* __restrict__ dw2, const float* __restrict__ db2,
           const float* __restrict__ sw2, const float* __restrict__ sb2,
           float* __restrict__ alc, float* __restrict__ alt, float* __restrict__ gam)
{
    __shared__ float red[12];
    const int row = blockIdx.x, tid = threadIdx.x, lane = tid & 63, wave = tid >> 6;
    const float* hc = Hdc + (long)row * NDC;
    const float* ht = Hdt + (long)row * NDT;
    float s1 = 0.f, s2 = 0.f, s3 = 0.f;
    for (int j = tid; j < 257; j += 256) { s1 += hc[j] * dw2[j]; s3 += ht[j] * dw2[j]; }
    for (int j = tid; j < 128; j += 256) s2 += hc[257 + j] * sw2[j];
    for (int o = 32; o > 0; o >>= 1) {
        s1 += __shfl_down(s1, o, 64); s2 += __shfl_down(s2, o, 64); s3 += __shfl_down(s3, o, 64);
    }
    if (lane == 0) { red[wave] = s1; red[4 + wave] = s2; red[8 + wave] = s3; }
    __syncthreads();
    if (tid == 0) {
        float a  = sigm(red[0] + red[1] + red[2] + red[3] + db2[0]);
        float g  = sigm(red[4] + red[5] + red[6] + red[7] + sb2[0]) + 0.5f;
        float at = sigm(red[8] + red[9] + red[10] + red[11] + db2[0]);
        if (isnan(a))  a  = 0.f;
        if (isnan(at)) at = 0.f;
        alc[row] = a; gam[row] = g; alt[row] = at;
    }
}

// scal layout: [0..19]=dc_sum [20..39]=dt_sum [40..59]=csq [60..79]=tsq
//              [80..99]=scale_c [100..119]=scale_t [120..139]=write_flag [140]=done
__global__ __launch_bounds__(256)
void update1(const float* __restrict__ c, const float* __restrict__ t,
             const float* __restrict__ fc, const float* __restrict__ ft,
             float* __restrict__ nc, float* __restrict__ nt,
             const float* __restrict__ damp,
             const float* __restrict__ alc, const float* __restrict__ alt,
             const float* __restrict__ gam,
             const float* __restrict__ csc, const float* __restrict__ tsc,
             float* __restrict__ scal, int step)
{
    __shared__ float red[16];
    const int row = blockIdx.x, tid = threadIdx.x, lane = tid & 63, wave = tid >> 6;
    const float gac = gam[row] * alc[row] * csc[0];
    const float gat = gam[row] * alt[row] * tsc[0];
    float sdc = 0.f, snc = 0.f, sdt = 0.f, snt = 0.f;
    for (int j = tid; j < F2E; j += 256) {
        float d = damp[j];
        float cv = c[(long)row * CLD + j];
        float ncv = d * cv + gac * fc[(long)row * CLD + j];
        nc[(long)row * CLD + j] = ncv;
        float dd = ncv - cv; sdc += dd * dd; snc += ncv * ncv;
        float tv = t[(long)row * CLD + j];
        float ntv = d * tv + gat * ft[(long)row * CLD + j];
        nt[(long)row * CLD + j] = ntv;
        dd = ntv - tv; sdt += dd * dd; snt += ntv * ntv;
    }
    for (int o = 32; o > 0; o >>= 1) {
        sdc += __shfl_down(sdc, o, 64); snc += __shfl_down(snc, o, 64);
        sdt += __shfl_down(sdt, o, 64); snt += __shfl_down(snt, o, 64);
    }
    if (lane == 0) { red[wave] = sdc; red[4 + wave] = snc; red[8 + wave] = sdt; red[12 + wave] = snt; }
    __syncthreads();
    if (tid == 0) {
        atomicAdd(&scal[0 + step],  sqrtf(red[0] + red[1] + red[2] + red[3]));
        atomicAdd(&scal[40 + step], red[4] + red[5] + red[6] + red[7]);
        atomicAdd(&scal[20 + step], sqrtf(red[8] + red[9] + red[10] + red[11]));
        atomicAdd(&scal[60 + step], red[12] + red[13] + red[14] + red[15]);
    }
}

__global__ void update2(float* scal, int step)
{
    if (threadIdx.x == 0 && blockIdx.x == 0) {
        float dc = scal[step] * (1.0f / 4096.0f);
        float dt = scal[20 + step] * (1.0f / 4096.0f);
        bool conv = (dc < 1e-3f) && (dt < 1e-3f);
        float done = scal[140];
        scal[120 + step] = (done != 0.f) ? 0.f : 1.f;
        float nrc = sqrtf(scal[40 + step]);
        float nrt = sqrtf(scal[60 + step]);
        scal[80 + step]  = conv ? 1.f : (nrc > 10.f ? 10.f / nrc : 1.f);
        scal[100 + step] = conv ? 1.f : (nrt > 10.f ? 10.f / nrt : 1.f);
        scal[140] = (done != 0.f || conv) ? 1.f : 0.f;
    }
}

__global__ __launch_bounds__(256)
void update3(float* __restrict__ c, float* __restrict__ t,
             const float* __restrict__ nc, const float* __restrict__ nt,
             bf16* __restrict__ X, bf16* __restrict__ Cb, bf16* __restrict__ Tb,
             const float* __restrict__ scal, int step)
{
    if (scal[120 + step] == 0.f) return;    // frozen after convergence
    const float sc = scal[80 + step], st = scal[100 + step];
    const int row = blockIdx.x;
    for (int j = threadIdx.x; j < F2E; j += 256) {
        float cv = sc * nc[(long)row * CLD + j];
        float tv = st * nt[(long)row * CLD + j];
        c[(long)row * CLD + j] = cv;
        t[(long)row * CLD + j] = tv;
        X[(long)row * XLD + j]       = __float2bfloat16(cv);
        X[(long)row * XLD + 514 + j] = __float2bfloat16(tv);
        Cb[(long)row * KDP + j] = __float2bfloat16(n2n(cv));
        Tb[(long)row * KDP + j] = __float2bfloat16(n2n(tv));
    }
}

// ---------------- host ----------------
extern "C" void kernel_launch(void* const* d_in, const int* in_sizes, int n_in,
                              void* d_out, int out_size, void* d_ws, size_t ws_size,
                              hipStream_t stream)
{
    (void)in_sizes; (void)n_in; (void)out_size; (void)ws_size;
    const float* carrier = (const float*)d_in[0];
    const float* traj    = (const float*)d_in[1];
    const float* srcp    = (const float*)d_in[2];
    const float* tgtp    = (const float*)d_in[3];
    const float* cw1 = (const float*)d_in[4];  const float* cb1 = (const float*)d_in[5];
    const float* cg  = (const float*)d_in[6];  const float* cbe = (const float*)d_in[7];
    const float* cw2 = (const float*)d_in[8];  const float* cb2 = (const float*)d_in[9];
    const float* tw1 = (const float*)d_in[10]; const float* tb1 = (const float*)d_in[11];
    const float* tg  = (const float*)d_in[12]; const float* tbe = (const float*)d_in[13];
    const float* tw2 = (const float*)d_in[14]; const float* tb2 = (const float*)d_in[15];
    const float* fd  = (const float*)d_in[16];
    const float* dw1 = (const float*)d_in[17]; const float* db1 = (const float*)d_in[18];
    const float* dw2 = (const float*)d_in[19]; const float* db2 = (const float*)d_in[20];
    const float* sw1 = (const float*)d_in[21]; const float* sb1 = (const float*)d_in[22];
    const float* sw2 = (const float*)d_in[23]; const float* sb2 = (const float*)d_in[24];
    const float* csc = (const float*)d_in[25]; const float* tsc = (const float*)d_in[26];

    char* p = (char*)d_ws;
    size_t off = 0;
    auto take = [&](size_t bytes) { size_t o = off; off += (bytes + 255) & ~(size_t)255; return o; };
    bf16*  X    = (bf16*) (p + take((size_t)RTOT * XLD * 2));
    bf16*  W1t  = (bf16*) (p + take((size_t)NT1 * XLD * 2));
    float* Y    = (float*)(p + take((size_t)RTOT * NT1 * 4));
    bf16*  H    = (bf16*) (p + take((size_t)RTOT * HLD * 2));
    bf16*  W2t  = (bf16*) (p + take((size_t)1280 * KH * 2));
    bf16*  Wdc  = (bf16*) (p + take((size_t)NDC * KDP * 2));
    bf16*  Wdt  = (bf16*) (p + take((size_t)NDT * KDP * 2));
    float* b1c  = (float*)(p + take(NT1 * 4));
    float* b2c  = (float*)(p + take(1280 * 4));
    float* bdc  = (float*)(p + take(NDC * 4));
    float* bdt  = (float*)(p + take(NDT * 4));
    float* RT   = (float*)(p + take(640L * 512 * 4));
    float* IT   = (float*)(p + take(512L * 640 * 4));
    float* damp = (float*)(p + take(F2E * 4));
    float* cbuf = (float*)(p + take((size_t)RTOT * CLD * 4));
    float* tbuf = (float*)(p + take((size_t)RTOT * CLD * 4));
    float* ncb  = (float*)(p + take((size_t)RTOT * CLD * 4));
    float* ntb  = (float*)(p + take((size_t)RTOT * CLD * 4));
    float* fcb  = (float*)(p + take((size_t)RTOT * CLD * 4));
    float* ftb  = (float*)(p + take((size_t)RTOT * CLD * 4));
    bf16*  Cbb  = (bf16*) (p + take((size_t)RTOT * KDP * 2));
    bf16*  Tbb  = (bf16*) (p + take((size_t)RTOT * KDP * 2));
    float* Hdc  = (float*)(p + take((size_t)RTOT * NDC * 4));
    float* Hdt  = (float*)(p + take((size_t)RTOT * NDT * 4));
    float* alc  = (float*)(p + take(RTOT * 4));
    float* alt  = (float*)(p + take(RTOT * 4));
    float* gam  = (float*)(p + take(RTOT * 4));
    float* scal = (float*)(p + take(1024));

    // d_ws is poisoned before every call: re-init everything that relies on zeros
    hipMemsetAsync(X,   0, (size_t)RTOT * XLD * 2, stream);
    hipMemsetAsync(H,   0, (size_t)RTOT * HLD * 2, stream);
    hipMemsetAsync(Cbb, 0, (size_t)RTOT * KDP * 2, stream);
    hipMemsetAsync(Tbb, 0, (size_t)RTOT * KDP * 2, stream);
    hipMemsetAsync(scal, 0, 1024, stream);

    build_tables<<<2560, 256, 0, stream>>>(RT, IT);
    build_damp<<<3, 256, 0, stream>>>(damp, fd);
    wprep<<<dim3(NT1, (XLD + 255) / 256), 256, 0, stream>>>(W1t, XLD, cw1, 2052, 1028, 0, tw1, 2052, 1028, 1152);
    wprep<<<dim3(1280, (KH + 255) / 256), 256, 0, stream>>>(W2t, KH, cw2, 1028, 514, 0, tw2, 1028, 514, 640);
    wprep<<<dim3(NDC, (KDP + 255) / 256), 256, 0, stream>>>(Wdc, KDP, dw1, 514, 257, 0, sw1, 514, 128, 257);
    wprep<<<dim3(NDT, (KDP + 255) / 256), 256, 0, stream>>>(Wdt, KDP, dw1, 514, 257, 0, nullptr, 0, 0, 0);
    bias_fill<<<(NT1 + 255) / 256, 256, 0, stream>>>(b1c, NT1, cb1, 1028, 0, tb1, 1028, 1152);
    bias_fill<<<(1280 + 255) / 256, 256, 0, stream>>>(b2c, 1280, cb2, 514, 0, tb2, 514, 640);
    bias_fill<<<(NDC + 255) / 256, 256, 0, stream>>>(bdc, NDC, db1, 257, 0, sb1, 128, 257);
    bias_fill<<<(NDT + 255) / 256, 256, 0, stream>>>(bdt, NDT, db1, 257, 0, nullptr, 0, 0);
    fill_xst<<<dim3(RTOT, 2), 256, 0, stream>>>(X, srcp, tgtp);

    // rfft (fp32 DFT-matmul); RT pad rows also zero the c/t pad columns
    sgemm_bt<<<dim3(64, 10), 256, 0, stream>>>(carrier, SP, RT, SP, cbuf, CLD, 32);
    sgemm_bt<<<dim3(64, 10), 256, 0, stream>>>(traj,    SP, RT, SP, tbuf, CLD, 32);
    initconv<<<RTOT, 256, 0, stream>>>(cbuf, tbuf, X, Cbb, Tbb);

    for (int s = 0; s < 20; ++s) {
        gemm_bt<0><<<dim3(32, 18), 256, 0, stream>>>(X, XLD, W1t, XLD, Y, NT1, b1c, 66);
        ln_gelu<<<dim3(RTOT, 2), 256, 0, stream>>>(Y, H, cg, cbe, tg, tbe);
        gemm_bt<1><<<dim3(32, 5), 256, 0, stream>>>(H, HLD, W2t, KH, fcb, CLD, b2c, 34);
        gemm_bt<1><<<dim3(32, 5), 256, 0, stream>>>(H + KH, HLD, W2t + (size_t)640 * KH, KH, ftb, CLD, b2c + 640, 34);
        gemm_bt<2><<<dim3(32, 4), 256, 0, stream>>>(Cbb, KDP, Wdc, KDP, Hdc, NDC, bdc, 18);
        gemm_bt<2><<<dim3(32, 3), 256, 0, stream>>>(Tbb, KDP, Wdt, KDP, Hdt, NDT, bdt, 18);
        heads<<<RTOT, 256, 0, stream>>>(Hdc, Hdt, dw2, db2, sw2, sb2, alc, alt, gam);
        update1<<<RTOT, 256, 0, stream>>>(cbuf, tbuf, fcb, ftb, ncb, ntb, damp, alc, alt, gam, csc, tsc, scal, s);
        update2<<<1, 64, 0, stream>>>(scal, s);
        update3<<<RTOT, 256, 0, stream>>>(cbuf, tbuf, ncb, ntb, X, Cbb, Tbb, scal, s);
    }

    float* out = (float*)d_out;
    sgemm_bt<<<dim3(64, 8), 256, 0, stream>>>(cbuf, CLD, IT, CLD, out, SP, 40);
    sgemm_bt<<<dim3(64, 8), 256, 0, stream>>>(tbuf, CLD, IT, CLD, out + (size_t)RTOT * SP, SP, 40);
}

// Round 3
// 4723.724 us; speedup vs baseline: 1.2271x; 1.2271x over previous
//
#include <hip/hip_runtime.h>
#include <hip/hip_bf16.h>
#include <math.h>

typedef __hip_bfloat16 bf16;
using s16x8 = __attribute__((ext_vector_type(8))) short;
using f32x4 = __attribute__((ext_vector_type(4))) float;
typedef __attribute__((address_space(1))) const unsigned int gu32;
typedef __attribute__((address_space(3))) unsigned int lu32;

#define RTOT 4096      // B*S rows
#define XLD  2112      // combined-input stride (K1 padded: 2052->2112)
#define NT1  2304      // GEMM1 padded N (2 nets x 1152, real 1028 each)
#define HLD  2176      // H stride (2 nets x 1088)
#define KH   1088      // GEMM2 K padded (1028->1088)
#define CLD  640       // c/t/fc/nc fp32 stride
#define KDP  576       // small-mlp K padded (514->576)
#define NDC  512       // d+s hidden padded (257+128=385 -> 512)
#define NDT  384       // d hidden padded (257 -> 384)
#define F2E  514
#define SP   512

__device__ __forceinline__ float gelu_ex(float x) {
    return 0.5f * x * (1.0f + erff(x * 0.70710678118654752f));
}
__device__ __forceinline__ float sigm(float x) { return 1.0f / (1.0f + expf(-x)); }
__device__ __forceinline__ float n2n(float x) {
    if (isnan(x)) return 0.0f;
    if (isinf(x)) return x > 0.0f ? 1e6f : -1e6f;
    return x;
}
__device__ __forceinline__ unsigned short bfb(float x) {
    __hip_bfloat16 h = __float2bfloat16(x);
    return *(unsigned short*)&h;
}
__device__ __forceinline__ unsigned packbf(float x, float y) {
    return (unsigned)bfb(x) | ((unsigned)bfb(y) << 16);
}
__device__ __forceinline__ void glds16(const bf16* g, short* l) {
    __builtin_amdgcn_global_load_lds((gu32*)g, (lu32*)l, 16, 0, 0);
}

// ---------------- bf16 MFMA GEMM: C[M,N] = A[M,K] * Bt[N,K]^T (+bias, epilogue) ----
// m97 structure: global_load_lds width-16 staging, linear LDS, 2 barriers/K-step.
// EPI: 0 = x+bias, 1 = tanh(x+bias), 2 = gelu(x+bias)
template<int EPI>
__global__ __launch_bounds__(256)
void gemm_bt(const bf16* __restrict__ A, int lda,
             const bf16* __restrict__ Bt, int ldb,
             float* __restrict__ C, int ldc,
             const float* __restrict__ bias, int ktiles)
{
    __shared__ __align__(16) short As[128 * 32];
    __shared__ __align__(16) short Bs[128 * 32];
    const int tid  = threadIdx.x;
    const int lane = tid & 63;
    const int wave = tid >> 6;
    const int l15  = lane & 15, kl = lane >> 4;
    const long mb = (long)blockIdx.x * 128;
    const long nb = (long)blockIdx.y * 128;
    const int wr = (wave >> 1) * 64;
    const int wc = (wave & 1) * 64;

    f32x4 acc[4][4] = {};

    // staging: wave w owns rows [w*32, w*32+32); 2 global_load_lds x 16 rows per operand.
    // LDS dest is wave-uniform base + lane*16B (linear); per-lane global src matches.
    const int grp_r = lane >> 2;            // 0..15
    const int gcol  = (lane & 3) * 8;       // shorts
    const bf16* gA0 = A  + (mb + wave * 32 + grp_r) * (long)lda + gcol;
    const bf16* gA1 = gA0 + 16 * (long)lda;
    const bf16* gB0 = Bt + (nb + wave * 32 + grp_r) * (long)ldb + gcol;
    const bf16* gB1 = gB0 + 16 * (long)ldb;
    short* lA0 = &As[(wave * 32) * 32];
    short* lA1 = &As[(wave * 32 + 16) * 32];
    short* lB0 = &Bs[(wave * 32) * 32];
    short* lB1 = &Bs[(wave * 32 + 16) * 32];

    for (int kt = 0; kt < ktiles; ++kt) {
        const long ko = (long)kt * 32;
        __syncthreads();                 // prev iteration's LDS reads done
        glds16(gA0 + ko, lA0);
        glds16(gA1 + ko, lA1);
        glds16(gB0 + ko, lB0);
        glds16(gB1 + ko, lB1);
        __syncthreads();                 // compiler drains vmcnt before barrier
        s16x8 af[4], bfr[4];
#pragma unroll
        for (int m = 0; m < 4; ++m) {
            int ar = wr + m * 16 + l15;
            af[m] = *reinterpret_cast<const s16x8*>(&As[ar * 32 + kl * 8]);
        }
#pragma unroll
        for (int n = 0; n < 4; ++n) {
            int br = wc + n * 16 + l15;
            bfr[n] = *reinterpret_cast<const s16x8*>(&Bs[br * 32 + kl * 8]);
        }
#pragma unroll
        for (int m = 0; m < 4; ++m)
#pragma unroll
            for (int n = 0; n < 4; ++n)
                acc[m][n] = __builtin_amdgcn_mfma_f32_16x16x32_bf16(af[m], bfr[n], acc[m][n], 0, 0, 0);
    }

#pragma unroll
    for (int m = 0; m < 4; ++m) {
        const long grow0 = mb + wr + m * 16 + kl * 4;
#pragma unroll
        for (int n = 0; n < 4; ++n) {
            const long gcol2 = nb + wc + n * 16 + l15;
            const float bb = bias[gcol2];
            f32x4 v = acc[m][n];
#pragma unroll
            for (int r = 0; r < 4; ++r) {
                float x = v[r] + bb;
                if (EPI == 1) x = tanhf(x);
                else if (EPI == 2) x = gelu_ex(x);
                C[(grow0 + r) * (long)ldc + gcol2] = x;
            }
        }
    }
}

// ---------------- fp32 SGEMM (rfft/irfft tables): C[M,N] = A[M,K] * Bt[N,K]^T -------
__global__ __launch_bounds__(256)
void sgemm_bt(const float* __restrict__ A, int lda,
              const float* __restrict__ Bt, int ldb,
              float* __restrict__ C, int ldc, int ktiles)
{
    __shared__ float As[64][17];
    __shared__ float Bs[64][17];
    const int tid = threadIdx.x;
    const int tx = tid & 15, ty = tid >> 4;
    const long mb = (long)blockIdx.x * 64, nb = (long)blockIdx.y * 64;
    float acc[4][4] = {};
    for (int kt = 0; kt < ktiles; ++kt) {
#pragma unroll
        for (int e = 0; e < 4; ++e) {
            int idx = e * 256 + tid;
            int r = idx >> 4, k = idx & 15;
            As[r][k] = A[(mb + r) * (long)lda + kt * 16 + k];
            Bs[r][k] = Bt[(nb + r) * (long)ldb + kt * 16 + k];
        }
        __syncthreads();
#pragma unroll
        for (int kk = 0; kk < 16; ++kk) {
            float a[4], b[4];
#pragma unroll
            for (int i = 0; i < 4; ++i) a[i] = As[ty * 4 + i][kk];
#pragma unroll
            for (int j = 0; j < 4; ++j) b[j] = Bs[tx * 4 + j][kk];
#pragma unroll
            for (int i = 0; i < 4; ++i)
#pragma unroll
                for (int j = 0; j < 4; ++j) acc[i][j] = fmaf(a[i], b[j], acc[i][j]);
        }
        __syncthreads();
    }
#pragma unroll
    for (int i = 0; i < 4; ++i)
#pragma unroll
        for (int j = 0; j < 4; ++j)
            C[(mb + ty * 4 + i) * (long)ldc + nb + tx * 4 + j] = acc[i][j];
}

// ---------------- setup kernels ----------------
__global__ void build_tables(float* __restrict__ RT, float* __restrict__ IT)
{
    long idx = (long)blockIdx.x * 256 + threadIdx.x;
    const double W = 6.283185307179586476925286766559005768 / 512.0;
    if (idx < 640L * 512) {                  // RT[640][512]: rfft rows (re/im interleaved)
        int r = (int)(idx >> 9), n = (int)(idx & 511);
        float v = 0.f;
        if (r < F2E) {
            int bin = r >> 1;
            int m = (bin * n) & 511;
            double ang = W * m;
            v = (r & 1) ? (float)(-sin(ang)) : (float)cos(ang);
        }
        RT[idx] = v;
    } else {
        long j2 = idx - 640L * 512;          // IT[512][640]: irfft rows
        if (j2 < 512L * 640) {
            int n = (int)(j2 / 640), j = (int)(j2 % 640);
            float v = 0.f;
            if (j < F2E) {
                int bin = j >> 1;
                int m = (bin * n) & 511;
                double ang = W * m;
                bool edge = (bin == 0 || bin == 256);
                double ck = edge ? 1.0 : 2.0;
                if (j & 1) v = edge ? 0.f : (float)(-ck * sin(ang) / 512.0);
                else       v = (float)(ck * cos(ang) / 512.0);
            }
            IT[j2] = v;
        }
    }
}

__global__ void build_damp(float* damp, const float* __restrict__ fd)
{
    int i = blockIdx.x * 256 + threadIdx.x;
    if (i < F2E) damp[i] = fd[i < 257 ? i : i - 257];   // torch repeat(...,2) tiling quirk
}

// transpose fp32 [K,N] weights into bf16 [rows=ldn][cols=ldk], zero-padded, 2 segments
__global__ void wprep(bf16* __restrict__ dst, int ldk,
                      const float* s0, int K0, int N0, int r00,
                      const float* s1, int K1, int N1, int r01)
{
    int r = blockIdx.x;
    int k = blockIdx.y * 256 + threadIdx.x;
    if (k >= ldk) return;
    float v = 0.f;
    if (s0 && r >= r00 && r < r00 + N0 && k < K0) v = s0[(long)k * N0 + (r - r00)];
    if (s1 && r >= r01 && r < r01 + N1 && k < K1) v = s1[(long)k * N1 + (r - r01)];
    dst[(long)r * ldk + k] = __float2bfloat16(v);
}

__global__ void bias_fill(float* __restrict__ dst, int n,
                          const float* s0, int l0, int o0,
                          const float* s1, int l1, int o1)
{
    int i = blockIdx.x * 256 + threadIdx.x;
    if (i >= n) return;
    float v = 0.f;
    if (s0 && i >= o0 && i < o0 + l0) v = s0[i - o0];
    if (s1 && i >= o1 && i < o1 + l1) v = s1[i - o1];
    dst[i] = v;
}

__global__ void fill_xst(bf16* __restrict__ X, const float* __restrict__ srcp,
                         const float* __restrict__ tgtp)
{
    int row = blockIdx.x;
    int j = blockIdx.y * 256 + threadIdx.x;   // grid.y=2 -> j<512
    int b = row >> 9;
    X[(long)row * XLD + 1028 + j] = __float2bfloat16(srcp[b * 513 + j]);
    X[(long)row * XLD + 1540 + j] = __float2bfloat16(tgtp[b * 513 + j]);
}

__global__ void initconv(const float* __restrict__ cb, const float* __restrict__ tb,
                         bf16* __restrict__ X, bf16* __restrict__ Cb, bf16* __restrict__ Tb)
{
    int row = blockIdx.x;
    for (int j = threadIdx.x; j < F2E; j += 256) {
        float cv = cb[(long)row * CLD + j], tv = tb[(long)row * CLD + j];
        X[(long)row * XLD + j]        = __float2bfloat16(cv);
        X[(long)row * XLD + 514 + j]  = __float2bfloat16(tv);
        Cb[(long)row * KDP + j] = __float2bfloat16(n2n(cv));
        Tb[(long)row * KDP + j] = __float2bfloat16(n2n(tv));
    }
}

// ---------------- per-step kernels (wave-per-row, vectorized) ----------------
__global__ __launch_bounds__(256)
void ln_gelu(const float* __restrict__ Y, bf16* __restrict__ H,
             const float* __restrict__ cg, const float* __restrict__ cbeta,
             const float* __restrict__ tg, const float* __restrict__ tbeta)
{
    const int lane = threadIdx.x & 63, wave = threadIdx.x >> 6;
    const int p = blockIdx.x * 4 + wave;      // 8192 (row,net) pairs
    const int row = p >> 1, net = p & 1;
    const float4* y4 = (const float4*)(Y + (long)row * NT1 + net * 1152);
    float4 v[4], vt = {0.f, 0.f, 0.f, 0.f};
    float s = 0.f;
#pragma unroll
    for (int k = 0; k < 4; ++k) {
        v[k] = y4[lane + k * 64];
        s += v[k].x + v[k].y + v[k].z + v[k].w;
    }
    if (lane == 0) { vt = y4[256]; s += vt.x + vt.y + vt.z + vt.w; }
#pragma unroll
    for (int o = 1; o < 64; o <<= 1) s += __shfl_xor(s, o, 64);
    const float mean = s * (1.0f / 1028.0f);
    float vs = 0.f;
#pragma unroll
    for (int k = 0; k < 4; ++k) {
        float a = v[k].x - mean, b = v[k].y - mean, c = v[k].z - mean, d = v[k].w - mean;
        vs += a * a + b * b + c * c + d * d;
    }
    if (lane == 0) {
        float a = vt.x - mean, b = vt.y - mean, c = vt.z - mean, d = vt.w - mean;
        vs += a * a + b * b + c * c + d * d;
    }
#pragma unroll
    for (int o = 1; o < 64; o <<= 1) vs += __shfl_xor(vs, o, 64);
    const float rs = rsqrtf(vs * (1.0f / 1028.0f) + 1e-5f);
    const float4* g4 = (const float4*)(net ? tg : cg);
    const float4* b4 = (const float4*)(net ? tbeta : cbeta);
    bf16* h = H + (long)row * HLD + (long)net * KH;
#pragma unroll
    for (int k = 0; k < 4; ++k) {
        int j = lane + k * 64;
        float4 gv = g4[j], bv = b4[j];
        ushort4 o;
        o.x = bfb(gelu_ex((v[k].x - mean) * rs * gv.x + bv.x));
        o.y = bfb(gelu_ex((v[k].y - mean) * rs * gv.y + bv.y));
        o.z = bfb(gelu_ex((v[k].z - mean) * rs * gv.z + bv.z));
        o.w = bfb(gelu_ex((v[k].w - mean) * rs * gv.w + bv.w));
        *(ushort4*)(&h[j * 4]) = o;
    }
    if (lane == 0) {
        float4 gv = g4[256], bv = b4[256];
        ushort4 o;
        o.x = bfb(gelu_ex((vt.x - mean) * rs * gv.x + bv.x));
        o.y = bfb(gelu_ex((vt.y - mean) * rs * gv.y + bv.y));
        o.z = bfb(gelu_ex((vt.z - mean) * rs * gv.z + bv.z));
        o.w = bfb(gelu_ex((vt.w - mean) * rs * gv.w + bv.w));
        *(ushort4*)(&h[1024]) = o;
    }
}

// fused heads + state update; per-block partials (NO atomics).
// part layout: part[q*1024 + block], q: 0=sum sqrt(dc), 1=sum sqrt(dt), 2=sum nc^2, 3=sum nt^2
__global__ __launch_bounds__(256)
void fused_update(const float* __restrict__ Hdc, const float* __restrict__ Hdt,
                  const float* __restrict__ dw2, const float* __restrict__ db2,
                  const float* __restrict__ sw2, const float* __restrict__ sb2,
                  const float* __restrict__ c, const float* __restrict__ t,
                  const float* __restrict__ fc, const float* __restrict__ ft,
                  float* __restrict__ nc, float* __restrict__ nt,
                  const float* __restrict__ damp,
                  const float* __restrict__ csc, const float* __restrict__ tsc,
                  float* __restrict__ part)
{
    __shared__ float red[16];
    const int tid = threadIdx.x, lane = tid & 63, wave = tid >> 6;
    const int row = blockIdx.x * 4 + wave;

    // --- heads: alpha_c, alpha_t, gamma for this row ---
    const float* hc = Hdc + (long)row * NDC;
    const float* ht = Hdt + (long)row * NDT;
    float s1 = 0.f, s2 = 0.f, s3 = 0.f;
#pragma unroll
    for (int k = 0; k < 4; ++k) {
        int j = lane + k * 64;
        s1 += hc[j] * dw2[j];
        s3 += ht[j] * dw2[j];
    }
    if (lane == 0) { s1 += hc[256] * dw2[256]; s3 += ht[256] * dw2[256]; }
#pragma unroll
    for (int k = 0; k < 2; ++k) {
        int j = lane + k * 64;
        s2 += hc[257 + j] * sw2[j];
    }
#pragma unroll
    for (int o = 1; o < 64; o <<= 1) {
        s1 += __shfl_xor(s1, o, 64);
        s2 += __shfl_xor(s2, o, 64);
        s3 += __shfl_xor(s3, o, 64);
    }
    float a  = sigm(s1 + db2[0]);
    float at = sigm(s3 + db2[0]);
    float g  = sigm(s2 + sb2[0]) + 0.5f;
    if (isnan(a))  a  = 0.f;
    if (isnan(at)) at = 0.f;
    const float gac = g * a  * csc[0];
    const float gat = g * at * tsc[0];

    // --- damp update + norms (float2, 257 f2 per row) ---
    const float2* c2  = (const float2*)(c  + (long)row * CLD);
    const float2* t2  = (const float2*)(t  + (long)row * CLD);
    const float2* fc2 = (const float2*)(fc + (long)row * CLD);
    const float2* ft2 = (const float2*)(ft + (long)row * CLD);
    float2* nc2 = (float2*)(nc + (long)row * CLD);
    float2* nt2 = (float2*)(nt + (long)row * CLD);
    const float2* d2 = (const float2*)damp;
    float sdc = 0.f, snc = 0.f, sdt = 0.f, snt = 0.f;
#pragma unroll
    for (int k = 0; k < 4; ++k) {
        int j = lane + k * 64;
        float2 dv = d2[j];
        float2 cv = c2[j], fv = fc2[j];
        float2 ncv = { dv.x * cv.x + gac * fv.x, dv.y * cv.y + gac * fv.y };
        nc2[j] = ncv;
        float dx = ncv.x - cv.x, dy = ncv.y - cv.y;
        sdc += dx * dx + dy * dy;
        snc += ncv.x * ncv.x + ncv.y * ncv.y;
        float2 tv = t2[j], gv = ft2[j];
        float2 ntv = { dv.x * tv.x + gat * gv.x, dv.y * tv.y + gat * gv.y };
        nt2[j] = ntv;
        dx = ntv.x - tv.x; dy = ntv.y - tv.y;
        sdt += dx * dx + dy * dy;
        snt += ntv.x * ntv.x + ntv.y * ntv.y;
    }
    if (lane == 0) {    // tail f2 index 256 (elements 512,513)
        float2 dv = d2[256];
        float2 cv = c2[256], fv = fc2[256];
        float2 ncv = { dv.x * cv.x + gac * fv.x, dv.y * cv.y + gac * fv.y };
        nc2[256] = ncv;
        float dx = ncv.x - cv.x, dy = ncv.y - cv.y;
        sdc += dx * dx + dy * dy;
        snc += ncv.x * ncv.x + ncv.y * ncv.y;
        float2 tv = t2[256], gv = ft2[256];
        float2 ntv = { dv.x * tv.x + gat * gv.x, dv.y * tv.y + gat * gv.y };
        nt2[256] = ntv;
        dx = ntv.x - tv.x; dy = ntv.y - tv.y;
        sdt += dx * dx + dy * dy;
        snt += ntv.x * ntv.x + ntv.y * ntv.y;
    }
#pragma unroll
    for (int o = 1; o < 64; o <<= 1) {
        sdc += __shfl_xor(sdc, o, 64);
        snc += __shfl_xor(snc, o, 64);
        sdt += __shfl_xor(sdt, o, 64);
        snt += __shfl_xor(snt, o, 64);
    }
    if (lane == 0) {
        red[wave * 4 + 0] = sqrtf(sdc);
        red[wave * 4 + 1] = sqrtf(sdt);
        red[wave * 4 + 2] = snc;
        red[wave * 4 + 3] = snt;
    }
    __syncthreads();
    if (tid < 4)
        part[tid * 1024 + blockIdx.x] =
            red[0 * 4 + tid] + red[1 * 4 + tid] + red[2 * 4 + tid] + red[3 * 4 + tid];
}

// scal layout: [80..99]=scale_c [100..119]=scale_t [120..139]=write_flag [140]=done
__global__ __launch_bounds__(256)
void update2(const float* __restrict__ part, float* __restrict__ scal, int step)
{
    __shared__ float red[4];
    const int tid = threadIdx.x, lane = tid & 63, wave = tid >> 6;
    const float* pq = part + wave * 1024;
    float s = 0.f;
#pragma unroll
    for (int k = 0; k < 16; ++k) s += pq[lane + k * 64];
#pragma unroll
    for (int o = 1; o < 64; o <<= 1) s += __shfl_xor(s, o, 64);
    if (lane == 0) red[wave] = s;
    __syncthreads();
    if (tid == 0) {
        float dc = red[0] * (1.0f / 4096.0f);
        float dt = red[1] * (1.0f / 4096.0f);
        bool conv = (dc < 1e-3f) && (dt < 1e-3f);
        float done = scal[140];
        scal[120 + step] = (done != 0.f) ? 0.f : 1.f;
        float nrc = sqrtf(red[2]);
        float nrt = sqrtf(red[3]);
        scal[80 + step]  = conv ? 1.f : (nrc > 10.f ? 10.f / nrc : 1.f);
        scal[100 + step] = conv ? 1.f : (nrt > 10.f ? 10.f / nrt : 1.f);
        scal[140] = (done != 0.f || conv) ? 1.f : 0.f;
    }
}

__global__ __launch_bounds__(256)
void update3(float* __restrict__ c, float* __restrict__ t,
             const float* __restrict__ nc, const float* __restrict__ nt,
             bf16* __restrict__ X, bf16* __restrict__ Cb, bf16* __restrict__ Tb,
             const float* __restrict__ scal, int step)
{
    if (scal[120 + step] == 0.f) return;    // frozen after convergence
    const float sc = scal[80 + step], st = scal[100 + step];
    const int lane = threadIdx.x & 63, wave = threadIdx.x >> 6;
    const int row = blockIdx.x * 4 + wave;
    const float2* nc2 = (const float2*)(nc + (long)row * CLD);
    const float2* nt2 = (const float2*)(nt + (long)row * CLD);
    float2* c2 = (float2*)(c + (long)row * CLD);
    float2* t2 = (float2*)(t + (long)row * CLD);
    bf16* xr = X  + (long)row * XLD;
    bf16* cb = Cb + (long)row * KDP;
    bf16* tb = Tb + (long)row * KDP;
#pragma unroll
    for (int k = 0; k < 5; ++k) {
        int j = lane + k * 64;
        if (k == 4 && lane > 0) break;      // only f2 idx 256 in tail
        float2 cv = nc2[j]; cv.x *= sc; cv.y *= sc;
        float2 tv = nt2[j]; tv.x *= st; tv.y *= st;
        c2[j] = cv;
        t2[j] = tv;
        *(unsigned*)(xr + j * 2)       = packbf(cv.x, cv.y);
        *(unsigned*)(xr + 514 + j * 2) = packbf(tv.x, tv.y);
        *(unsigned*)(cb + j * 2) = packbf(n2n(cv.x), n2n(cv.y));
        *(unsigned*)(tb + j * 2) = packbf(n2n(tv.x), n2n(tv.y));
    }
}

// ---------------- host ----------------
extern "C" void kernel_launch(void* const* d_in, const int* in_sizes, int n_in,
                              void* d_out, int out_size, void* d_ws, size_t ws_size,
                              hipStream_t stream)
{
    (void)in_sizes; (void)n_in; (void)out_size; (void)ws_size;
    const float* carrier = (const float*)d_in[0];
    const float* traj    = (const float*)d_in[1];
    const float* srcp    = (const float*)d_in[2];
    const float* tgtp    = (const float*)d_in[3];
    const float* cw1 = (const float*)d_in[4];  const float* cb1 = (const float*)d_in[5];
    const float* cg  = (const float*)d_in[6];  const float* cbe = (const float*)d_in[7];
    const float* cw2 = (const float*)d_in[8];  const float* cb2 = (const float*)d_in[9];
    const float* tw1 = (const float*)d_in[10]; const float* tb1 = (const float*)d_in[11];
    const float* tg  = (const float*)d_in[12]; const float* tbe = (const float*)d_in[13];
    const float* tw2 = (const float*)d_in[14]; const float* tb2 = (const float*)d_in[15];
    const float* fd  = (const float*)d_in[16];
    const float* dw1 = (const float*)d_in[17]; const float* db1 = (const float*)d_in[18];
    const float* dw2 = (const float*)d_in[19]; const float* db2 = (const float*)d_in[20];
    const float* sw1 = (const float*)d_in[21]; const float* sb1 = (const float*)d_in[22];
    const float* sw2 = (const float*)d_in[23]; const float* sb2 = (const float*)d_in[24];
    const float* csc = (const float*)d_in[25]; const float* tsc = (const float*)d_in[26];

    char* p = (char*)d_ws;
    size_t off = 0;
    auto take = [&](size_t bytes) { size_t o = off; off += (bytes + 255) & ~(size_t)255; return o; };
    bf16*  X    = (bf16*) (p + take((size_t)RTOT * XLD * 2));
    bf16*  W1t  = (bf16*) (p + take((size_t)NT1 * XLD * 2));
    float* Y    = (float*)(p + take((size_t)RTOT * NT1 * 4));
    bf16*  H    = (bf16*) (p + take((size_t)RTOT * HLD * 2));
    bf16*  W2t  = (bf16*) (p + take((size_t)1280 * KH * 2));
    bf16*  Wdc  = (bf16*) (p + take((size_t)NDC * KDP * 2));
    bf16*  Wdt  = (bf16*) (p + take((size_t)NDT * KDP * 2));
    float* b1c  = (float*)(p + take(NT1 * 4));
    float* b2c  = (float*)(p + take(1280 * 4));
    float* bdc  = (float*)(p + take(NDC * 4));
    float* bdt  = (float*)(p + take(NDT * 4));
    float* RT   = (float*)(p + take(640L * 512 * 4));
    float* IT   = (float*)(p + take(512L * 640 * 4));
    float* damp = (float*)(p + take(F2E * 4));
    float* cbuf = (float*)(p + take((size_t)RTOT * CLD * 4));
    float* tbuf = (float*)(p + take((size_t)RTOT * CLD * 4));
    float* ncb  = (float*)(p + take((size_t)RTOT * CLD * 4));
    float* ntb  = (float*)(p + take((size_t)RTOT * CLD * 4));
    float* fcb  = (float*)(p + take((size_t)RTOT * CLD * 4));
    float* ftb  = (float*)(p + take((size_t)RTOT * CLD * 4));
    bf16*  Cbb  = (bf16*) (p + take((size_t)RTOT * KDP * 2));
    bf16*  Tbb  = (bf16*) (p + take((size_t)RTOT * KDP * 2));
    float* Hdc  = (float*)(p + take((size_t)RTOT * NDC * 4));
    float* Hdt  = (float*)(p + take((size_t)RTOT * NDT * 4));
    float* part = (float*)(p + take(4096 * 4));
    float* scal = (float*)(p + take(1024));

    // d_ws is poisoned before every call: re-init everything that relies on zeros
    hipMemsetAsync(X,   0, (size_t)RTOT * XLD * 2, stream);
    hipMemsetAsync(H,   0, (size_t)RTOT * HLD * 2, stream);
    hipMemsetAsync(Cbb, 0, (size_t)RTOT * KDP * 2, stream);
    hipMemsetAsync(Tbb, 0, (size_t)RTOT * KDP * 2, stream);
    hipMemsetAsync(scal, 0, 1024, stream);

    build_tables<<<2560, 256, 0, stream>>>(RT, IT);
    build_damp<<<3, 256, 0, stream>>>(damp, fd);
    wprep<<<dim3(NT1, (XLD + 255) / 256), 256, 0, stream>>>(W1t, XLD, cw1, 2052, 1028, 0, tw1, 2052, 1028, 1152);
    wprep<<<dim3(1280, (KH + 255) / 256), 256, 0, stream>>>(W2t, KH, cw2, 1028, 514, 0, tw2, 1028, 514, 640);
    wprep<<<dim3(NDC, (KDP + 255) / 256), 256, 0, stream>>>(Wdc, KDP, dw1, 514, 257, 0, sw1, 514, 128, 257);
    wprep<<<dim3(NDT, (KDP + 255) / 256), 256, 0, stream>>>(Wdt, KDP, dw1, 514, 257, 0, nullptr, 0, 0, 0);
    bias_fill<<<(NT1 + 255) / 256, 256, 0, stream>>>(b1c, NT1, cb1, 1028, 0, tb1, 1028, 1152);
    bias_fill<<<(1280 + 255) / 256, 256, 0, stream>>>(b2c, 1280, cb2, 514, 0, tb2, 514, 640);
    bias_fill<<<(NDC + 255) / 256, 256, 0, stream>>>(bdc, NDC, db1, 257, 0, sb1, 128, 257);
    bias_fill<<<(NDT + 255) / 256, 256, 0, stream>>>(bdt, NDT, db1, 257, 0, nullptr, 0, 0);
    fill_xst<<<dim3(RTOT, 2), 256, 0, stream>>>(X, srcp, tgtp);

    // rfft (fp32 DFT-matmul); RT pad rows also zero the c/t pad columns
    sgemm_bt<<<dim3(64, 10), 256, 0, stream>>>(carrier, SP, RT, SP, cbuf, CLD, 32);
    sgemm_bt<<<dim3(64, 10), 256, 0, stream>>>(traj,    SP, RT, SP, tbuf, CLD, 32);
    initconv<<<RTOT, 256, 0, stream>>>(cbuf, tbuf, X, Cbb, Tbb);

    for (int s = 0; s < 20; ++s) {
        gemm_bt<0><<<dim3(32, 18), 256, 0, stream>>>(X, XLD, W1t, XLD, Y, NT1, b1c, 66);
        ln_gelu<<<2048, 256, 0, stream>>>(Y, H, cg, cbe, tg, tbe);
        gemm_bt<1><<<dim3(32, 5), 256, 0, stream>>>(H, HLD, W2t, KH, fcb, CLD, b2c, 34);
        gemm_bt<1><<<dim3(32, 5), 256, 0, stream>>>(H + KH, HLD, W2t + (size_t)640 * KH, KH, ftb, CLD, b2c + 640, 34);
        gemm_bt<2><<<dim3(32, 4), 256, 0, stream>>>(Cbb, KDP, Wdc, KDP, Hdc, NDC, bdc, 18);
        gemm_bt<2><<<dim3(32, 3), 256, 0, stream>>>(Tbb, KDP, Wdt, KDP, Hdt, NDT, bdt, 18);
        fused_update<<<1024, 256, 0, stream>>>(Hdc, Hdt, dw2, db2, sw2, sb2,
                                               cbuf, tbuf, fcb, ftb, ncb, ntb,
                                               damp, csc, tsc, part);
        update2<<<1, 256, 0, stream>>>(part, scal, s);
        update3<<<1024, 256, 0, stream>>>(cbuf, tbuf, ncb, ntb, X, Cbb, Tbb, scal, s);
    }

    float* out = (float*)d_out;
    sgemm_bt<<<dim3(64, 8), 256, 0, stream>>>(cbuf, CLD, IT, CLD, out, SP, 40);
    sgemm_bt<<<dim3(64, 8), 256, 0, stream>>>(tbuf, CLD, IT, CLD, out + (size_t)RTOT * SP, SP, 40);
}

// Round 6
// 3140.624 us; speedup vs baseline: 1.8457x; 1.5041x over previous
//
#include <hip/hip_runtime.h>
#include <hip/hip_bf16.h>
#include <math.h>

typedef __hip_bfloat16 bf16;
using s16x8 = __attribute__((ext_vector_type(8))) short;
using f32x4 = __attribute__((ext_vector_type(4))) float;
typedef __attribute__((address_space(1))) const unsigned int gu32;
typedef __attribute__((address_space(3))) unsigned int lu32;

#define RTOT 4096      // B*S rows
#define XCT  1056      // c,t input stride (K1 halved: 1028->1056)
#define NT1  2304      // GEMM1 padded N (2 nets x 1152, real 1028 each)
#define HLD  2176      // H stride (2 nets x 1088)
#define KH   1088      // GEMM2 K padded (1028->1088)
#define CLD  640       // c/t/fc/nc fp32 stride
#define KDP  576       // small-mlp K padded (514->576)
#define NDC  512       // d+s hidden padded (257+128=385 -> 512)
#define F2E  514
#define SP   512

__device__ __forceinline__ float gelu_ex(float x) {
    return 0.5f * x * (1.0f + erff(x * 0.70710678118654752f));
}
__device__ __forceinline__ float sigm(float x) { return 1.0f / (1.0f + expf(-x)); }
__device__ __forceinline__ float n2n(float x) {
    if (isnan(x)) return 0.0f;
    if (isinf(x)) return x > 0.0f ? 1e6f : -1e6f;
    return x;
}
__device__ __forceinline__ unsigned short bfb(float x) {
    __hip_bfloat16 h = __float2bfloat16(x);
    return *(unsigned short*)&h;
}
__device__ __forceinline__ unsigned packbf(float x, float y) {
    return (unsigned)bfb(x) | ((unsigned)bfb(y) << 16);
}
__device__ __forceinline__ void glds16(const bf16* g, short* l) {
    __builtin_amdgcn_global_load_lds((gu32*)g, (lu32*)l, 16, 0, 0);
}

// ---------------- bf16 MFMA GEMM: C[M,N] = A[M,K] * Bt[N,K]^T (+bias, epilogue) ----
// m97 structure: global_load_lds width-16 staging, linear LDS, 2 barriers/K-step.
// EPI: 0 = x+bias, 1 = tanh(x+bias), 2 = gelu(x+bias)
// bias_ld != 0 -> 2D bias indexed by batch row (mb>>9). z-offsets allow merged launches.
template<int EPI>
__global__ __launch_bounds__(256)
void gemm_bt(const bf16* __restrict__ A, int lda,
             const bf16* __restrict__ Bt, int ldb,
             float* __restrict__ C, int ldc,
             const float* __restrict__ bias, int bias_ld, int ktiles,
             long zA, long zB, long zC, long zBias)
{
    A    += (long)blockIdx.z * zA;
    Bt   += (long)blockIdx.z * zB;
    C    += (long)blockIdx.z * zC;
    bias += (long)blockIdx.z * zBias;

    __shared__ __align__(16) short As[128 * 32];
    __shared__ __align__(16) short Bs[128 * 32];
    const int tid  = threadIdx.x;
    const int lane = tid & 63;
    const int wave = tid >> 6;
    const int l15  = lane & 15, kl = lane >> 4;
    const long mb = (long)blockIdx.x * 128;
    const long nb = (long)blockIdx.y * 128;
    const int wr = (wave >> 1) * 64;
    const int wc = (wave & 1) * 64;

    f32x4 acc[4][4] = {};

    // staging: wave w owns rows [w*32, w*32+32); 2 global_load_lds x 16 rows per operand.
    const int grp_r = lane >> 2;            // 0..15
    const int gcol  = (lane & 3) * 8;       // shorts
    const bf16* gA0 = A  + (mb + wave * 32 + grp_r) * (long)lda + gcol;
    const bf16* gA1 = gA0 + 16 * (long)lda;
    const bf16* gB0 = Bt + (nb + wave * 32 + grp_r) * (long)ldb + gcol;
    const bf16* gB1 = gB0 + 16 * (long)ldb;
    short* lA0 = &As[(wave * 32) * 32];
    short* lA1 = &As[(wave * 32 + 16) * 32];
    short* lB0 = &Bs[(wave * 32) * 32];
    short* lB1 = &Bs[(wave * 32 + 16) * 32];

    for (int kt = 0; kt < ktiles; ++kt) {
        const long ko = (long)kt * 32;
        __syncthreads();                 // prev iteration's LDS reads done
        glds16(gA0 + ko, lA0);
        glds16(gA1 + ko, lA1);
        glds16(gB0 + ko, lB0);
        glds16(gB1 + ko, lB1);
        __syncthreads();                 // compiler drains vmcnt before barrier
        s16x8 af[4], bfr[4];
#pragma unroll
        for (int m = 0; m < 4; ++m) {
            int ar = wr + m * 16 + l15;
            af[m] = *reinterpret_cast<const s16x8*>(&As[ar * 32 + kl * 8]);
        }
#pragma unroll
        for (int n = 0; n < 4; ++n) {
            int br = wc + n * 16 + l15;
            bfr[n] = *reinterpret_cast<const s16x8*>(&Bs[br * 32 + kl * 8]);
        }
#pragma unroll
        for (int m = 0; m < 4; ++m)
#pragma unroll
            for (int n = 0; n < 4; ++n)
                acc[m][n] = __builtin_amdgcn_mfma_f32_16x16x32_bf16(af[m], bfr[n], acc[m][n], 0, 0, 0);
    }

    const float* brow = bias + (bias_ld ? (long)(mb >> 9) * bias_ld : 0);
#pragma unroll
    for (int m = 0; m < 4; ++m) {
        const long grow0 = mb + wr + m * 16 + kl * 4;
#pragma unroll
        for (int n = 0; n < 4; ++n) {
            const long gcol2 = nb + wc + n * 16 + l15;
            const float bb = brow[gcol2];
            f32x4 v = acc[m][n];
#pragma unroll
            for (int r = 0; r < 4; ++r) {
                float x = v[r] + bb;
                if (EPI == 1) x = tanhf(x);
                else if (EPI == 2) x = gelu_ex(x);
                C[(grow0 + r) * (long)ldc + gcol2] = x;
            }
        }
    }
}

// ---------------- fp32 SGEMM (rfft/irfft tables): C[M,N] = A[M,K] * Bt[N,K]^T -------
// Transposed LDS ([k][m]/[k][n]) -> float4 global loads + ds_read_b128 fragments.
__global__ __launch_bounds__(256)
void sgemm_bt(const float* __restrict__ A, int lda,
              const float* __restrict__ Bt, int ldb,
              float* __restrict__ C, int ldc, int ktiles)
{
    __shared__ float As[16][68];   // [k][m], 68 = 64 + 4 pad (16B-aligned rows: 68*4=272)
    __shared__ float Bs[16][68];   // [k][n]
    const int tid = threadIdx.x;
    const int tx = tid & 15, ty = tid >> 4;
    const int lr = tid >> 2, lc = (tid & 3) * 4;     // load: row 0..63, col 4-chunk
    const long mb = (long)blockIdx.x * 64, nb = (long)blockIdx.y * 64;
    float acc[4][4] = {};
    const float* Ap = A  + (mb + lr) * (long)lda + lc;
    const float* Bp = Bt + (nb + lr) * (long)ldb + lc;
    for (int kt = 0; kt < ktiles; ++kt) {
        float4 av = *(const float4*)(Ap + kt * 16);
        float4 bv = *(const float4*)(Bp + kt * 16);
        __syncthreads();
        As[lc + 0][lr] = av.x; As[lc + 1][lr] = av.y;
        As[lc + 2][lr] = av.z; As[lc + 3][lr] = av.w;
        Bs[lc + 0][lr] = bv.x; Bs[lc + 1][lr] = bv.y;
        Bs[lc + 2][lr] = bv.z; Bs[lc + 3][lr] = bv.w;
        __syncthreads();
#pragma unroll
        for (int kk = 0; kk < 16; ++kk) {
            float4 a = *(const float4*)&As[kk][ty * 4];
            float4 b = *(const float4*)&Bs[kk][tx * 4];
            acc[0][0] = fmaf(a.x, b.x, acc[0][0]); acc[0][1] = fmaf(a.x, b.y, acc[0][1]);
            acc[0][2] = fmaf(a.x, b.z, acc[0][2]); acc[0][3] = fmaf(a.x, b.w, acc[0][3]);
            acc[1][0] = fmaf(a.y, b.x, acc[1][0]); acc[1][1] = fmaf(a.y, b.y, acc[1][1]);
            acc[1][2] = fmaf(a.y, b.z, acc[1][2]); acc[1][3] = fmaf(a.y, b.w, acc[1][3]);
            acc[2][0] = fmaf(a.z, b.x, acc[2][0]); acc[2][1] = fmaf(a.z, b.y, acc[2][1]);
            acc[2][2] = fmaf(a.z, b.z, acc[2][2]); acc[2][3] = fmaf(a.z, b.w, acc[2][3]);
            acc[3][0] = fmaf(a.w, b.x, acc[3][0]); acc[3][1] = fmaf(a.w, b.y, acc[3][1]);
            acc[3][2] = fmaf(a.w, b.z, acc[3][2]); acc[3][3] = fmaf(a.w, b.w, acc[3][3]);
        }
    }
#pragma unroll
    for (int i = 0; i < 4; ++i) {
        float4 st = { acc[i][0], acc[i][1], acc[i][2], acc[i][3] };
        *(float4*)&C[(mb + ty * 4 + i) * (long)ldc + nb + tx * 4] = st;
    }
}

// ---------------- setup kernels ----------------
__global__ void build_tables(float* __restrict__ RT, float* __restrict__ IT)
{
    long idx = (long)blockIdx.x * 256 + threadIdx.x;
    const double W = 6.283185307179586476925286766559005768 / 512.0;
    if (idx < 640L * 512) {                  // RT[640][512]: rfft rows (re/im interleaved)
        int r = (int)(idx >> 9), n = (int)(idx & 511);
        float v = 0.f;
        if (r < F2E) {
            int bin = r >> 1;
            int m = (bin * n) & 511;
            double ang = W * m;
            v = (r & 1) ? (float)(-sin(ang)) : (float)cos(ang);
        }
        RT[idx] = v;
    } else {
        long j2 = idx - 640L * 512;          // IT[512][640]: irfft rows
        if (j2 < 512L * 640) {
            int n = (int)(j2 / 640), j = (int)(j2 % 640);
            float v = 0.f;
            if (j < F2E) {
                int bin = j >> 1;
                int m = (bin * n) & 511;
                double ang = W * m;
                bool edge = (bin == 0 || bin == 256);
                double ck = edge ? 1.0 : 2.0;
                if (j & 1) v = edge ? 0.f : (float)(-ck * sin(ang) / 512.0);
                else       v = (float)(ck * cos(ang) / 512.0);
            }
            IT[j2] = v;
        }
    }
}

__global__ void build_damp(float* damp, const float* __restrict__ fd)
{
    int i = blockIdx.x * 256 + threadIdx.x;
    if (i < F2E) damp[i] = fd[i < 257 ? i : i - 257];   // torch repeat(...,2) tiling quirk
}

// Ybase[b][n] = b1[n] + sum_k [src,tgt][b][k] * W1[1028+k][n]  (src/tgt step-invariant)
__global__ void ybase_build(const float* __restrict__ srcp, const float* __restrict__ tgtp,
                            const float* __restrict__ cw1, const float* __restrict__ cb1,
                            const float* __restrict__ tw1, const float* __restrict__ tb1,
                            float* __restrict__ Yb)
{
    const int b = blockIdx.x;
    const int n = blockIdx.y * 256 + threadIdx.x;
    if (n >= NT1) return;
    float acc = 0.f;
    const bool isT = n >= 1152;
    const int nn = isT ? n - 1152 : n;
    if (nn < 1028) {
        const float* w  = isT ? tw1 : cw1;
        acc = (isT ? tb1 : cb1)[nn];
        const float* wst = w + (size_t)1028 * 1028 + nn;
        const float* wtg = w + (size_t)1540 * 1028 + nn;
        const float* s = srcp + b * 513;
        const float* t = tgtp + b * 513;
        for (int k = 0; k < 512; ++k) {
            acc = fmaf(s[k], wst[(size_t)k * 1028], acc);
            acc = fmaf(t[k], wtg[(size_t)k * 1028], acc);
        }
    }
    Yb[b * NT1 + n] = acc;
}

// transpose fp32 [K,N] weights into bf16 [rows=ldn][cols=ldk], zero-padded, 2 segments
__global__ void wprep(bf16* __restrict__ dst, int ldk,
                      const float* s0, int K0, int N0, int r00,
                      const float* s1, int K1, int N1, int r01)
{
    int r = blockIdx.x;
    int k = blockIdx.y * 256 + threadIdx.x;
    if (k >= ldk) return;
    float v = 0.f;
    if (s0 && r >= r00 && r < r00 + N0 && k < K0) v = s0[(long)k * N0 + (r - r00)];
    if (s1 && r >= r01 && r < r01 + N1 && k < K1) v = s1[(long)k * N1 + (r - r01)];
    dst[(long)r * ldk + k] = __float2bfloat16(v);
}

__global__ void bias_fill(float* __restrict__ dst, int n,
                          const float* s0, int l0, int o0,
                          const float* s1, int l1, int o1)
{
    int i = blockIdx.x * 256 + threadIdx.x;
    if (i >= n) return;
    float v = 0.f;
    if (s0 && i >= o0 && i < o0 + l0) v = s0[i - o0];
    if (s1 && i >= o1 && i < o1 + l1) v = s1[i - o1];
    dst[i] = v;
}

__global__ void initconv(const float* __restrict__ cb, const float* __restrict__ tb,
                         bf16* __restrict__ X, bf16* __restrict__ Cb, bf16* __restrict__ Tb)
{
    int row = blockIdx.x;
    for (int j = threadIdx.x; j < F2E; j += 256) {
        float cv = cb[(long)row * CLD + j], tv = tb[(long)row * CLD + j];
        X[(long)row * XCT + j]        = __float2bfloat16(cv);
        X[(long)row * XCT + 514 + j]  = __float2bfloat16(tv);
        Cb[(long)row * KDP + j] = __float2bfloat16(n2n(cv));
        Tb[(long)row * KDP + j] = __float2bfloat16(n2n(tv));
    }
}

// zero the K-pad columns of Xct once (pads never rewritten; W1ct pad is also 0,
// but keep both clean so poison can never reach the MFMA inputs as large values)
__global__ void xpad_zero(bf16* __restrict__ X)
{
    int row = blockIdx.x;
    int j = 1028 + threadIdx.x;          // 28 pad cols, 32 threads
    if (j < XCT) X[(long)row * XCT + j] = __float2bfloat16(0.f);
}

// ---------------- per-step kernels (wave-per-row, vectorized) ----------------
__global__ __launch_bounds__(256)
void ln_gelu(const float* __restrict__ Y, bf16* __restrict__ H,
             const float* __restrict__ cg, const float* __restrict__ cbeta,
             const float* __restrict__ tg, const float* __restrict__ tbeta)
{
    const int lane = threadIdx.x & 63, wave = threadIdx.x >> 6;
    const int p = blockIdx.x * 4 + wave;      // 8192 (row,net) pairs
    const int row = p >> 1, net = p & 1;
    const float4* y4 = (const float4*)(Y + (long)row * NT1 + net * 1152);
    float4 v[4], vt = {0.f, 0.f, 0.f, 0.f};
    float s = 0.f;
#pragma unroll
    for (int k = 0; k < 4; ++k) {
        v[k] = y4[lane + k * 64];
        s += v[k].x + v[k].y + v[k].z + v[k].w;
    }
    if (lane == 0) { vt = y4[256]; s += vt.x + vt.y + vt.z + vt.w; }
#pragma unroll
    for (int o = 1; o < 64; o <<= 1) s += __shfl_xor(s, o, 64);
    const float mean = s * (1.0f / 1028.0f);
    float vs = 0.f;
#pragma unroll
    for (int k = 0; k < 4; ++k) {
        float a = v[k].x - mean, b = v[k].y - mean, c = v[k].z - mean, d = v[k].w - mean;
        vs += a * a + b * b + c * c + d * d;
    }
    if (lane == 0) {
        float a = vt.x - mean, b = vt.y - mean, c = vt.z - mean, d = vt.w - mean;
        vs += a * a + b * b + c * c + d * d;
    }
#pragma unroll
    for (int o = 1; o < 64; o <<= 1) vs += __shfl_xor(vs, o, 64);
    const float rs = rsqrtf(vs * (1.0f / 1028.0f) + 1e-5f);
    const float4* g4 = (const float4*)(net ? tg : cg);
    const float4* b4 = (const float4*)(net ? tbeta : cbeta);
    bf16* h = H + (long)row * HLD + (long)net * KH;
#pragma unroll
    for (int k = 0; k < 4; ++k) {
        int j = lane + k * 64;
        float4 gv = g4[j], bv = b4[j];
        ushort4 o;
        o.x = bfb(gelu_ex((v[k].x - mean) * rs * gv.x + bv.x));
        o.y = bfb(gelu_ex((v[k].y - mean) * rs * gv.y + bv.y));
        o.z = bfb(gelu_ex((v[k].z - mean) * rs * gv.z + bv.z));
        o.w = bfb(gelu_ex((v[k].w - mean) * rs * gv.w + bv.w));
        *(ushort4*)(&h[j * 4]) = o;
    }
    if (lane == 0) {
        float4 gv = g4[256], bv = b4[256];
        ushort4 o;
        o.x = bfb(gelu_ex((vt.x - mean) * rs * gv.x + bv.x));
        o.y = bfb(gelu_ex((vt.y - mean) * rs * gv.y + bv.y));
        o.z = bfb(gelu_ex((vt.z - mean) * rs * gv.z + bv.z));
        o.w = bfb(gelu_ex((vt.w - mean) * rs * gv.w + bv.w));
        *(ushort4*)(&h[1024]) = o;
    }
}

// fused heads + state update; per-block partials (NO atomics).
// Hd stacked: rows 0..4095 = c-branch (cols 0..384 used), rows 4096..8191 = t-branch.
// part layout: part[q*1024 + block], q: 0=sum sqrt(dc), 1=sum sqrt(dt), 2=sum nc^2, 3=sum nt^2
__global__ __launch_bounds__(256)
void fused_update(const float* __restrict__ Hd,
                  const float* __restrict__ dw2, const float* __restrict__ db2,
                  const float* __restrict__ sw2, const float* __restrict__ sb2,
                  const float* __restrict__ c, const float* __restrict__ t,
                  const float* __restrict__ fc, const float* __restrict__ ft,
                  float* __restrict__ nc, float* __restrict__ nt,
                  const float* __restrict__ damp,
                  const float* __restrict__ csc, const float* __restrict__ tsc,
                  float* __restrict__ part)
{
    __shared__ float red[16];
    const int tid = threadIdx.x, lane = tid & 63, wave = tid >> 6;
    const int row = blockIdx.x * 4 + wave;

    // --- heads: alpha_c, alpha_t, gamma for this row ---
    const float* hc = Hd + (long)row * NDC;
    const float* ht = Hd + (long)(4096 + row) * NDC;
    float s1 = 0.f, s2 = 0.f, s3 = 0.f;
#pragma unroll
    for (int k = 0; k < 4; ++k) {
        int j = lane + k * 64;
        s1 += hc[j] * dw2[j];
        s3 += ht[j] * dw2[j];
    }
    if (lane == 0) { s1 += hc[256] * dw2[256]; s3 += ht[256] * dw2[256]; }
#pragma unroll
    for (int k = 0; k < 2; ++k) {
        int j = lane + k * 64;
        s2 += hc[257 + j] * sw2[j];
    }
#pragma unroll
    for (int o = 1; o < 64; o <<= 1) {
        s1 += __shfl_xor(s1, o, 64);
        s2 += __shfl_xor(s2, o, 64);
        s3 += __shfl_xor(s3, o, 64);
    }
    float a  = sigm(s1 + db2[0]);
    float at = sigm(s3 + db2[0]);
    float g  = sigm(s2 + sb2[0]) + 0.5f;
    if (isnan(a))  a  = 0.f;
    if (isnan(at)) at = 0.f;
    const float gac = g * a  * csc[0];
    const float gat = g * at * tsc[0];

    // --- damp update + norms (float2, 257 f2 per row) ---
    const float2* c2  = (const float2*)(c  + (long)row * CLD);
    const float2* t2  = (const float2*)(t  + (long)row * CLD);
    const float2* fc2 = (const float2*)(fc + (long)row * CLD);
    const float2* ft2 = (const float2*)(ft + (long)row * CLD);
    float2* nc2 = (float2*)(nc + (long)row * CLD);
    float2* nt2 = (float2*)(nt + (long)row * CLD);
    const float2* d2 = (const float2*)damp;
    float sdc = 0.f, snc = 0.f, sdt = 0.f, snt = 0.f;
#pragma unroll
    for (int k = 0; k < 4; ++k) {
        int j = lane + k * 64;
        float2 dv = d2[j];
        float2 cv = c2[j], fv = fc2[j];
        float2 ncv = { dv.x * cv.x + gac * fv.x, dv.y * cv.y + gac * fv.y };
        nc2[j] = ncv;
        float dx = ncv.x - cv.x, dy = ncv.y - cv.y;
        sdc += dx * dx + dy * dy;
        snc += ncv.x * ncv.x + ncv.y * ncv.y;
        float2 tv = t2[j], gv = ft2[j];
        float2 ntv = { dv.x * tv.x + gat * gv.x, dv.y * tv.y + gat * gv.y };
        nt2[j] = ntv;
        dx = ntv.x - tv.x; dy = ntv.y - tv.y;
        sdt += dx * dx + dy * dy;
        snt += ntv.x * ntv.x + ntv.y * ntv.y;
    }
    if (lane == 0) {    // tail f2 index 256 (elements 512,513)
        float2 dv = d2[256];
        float2 cv = c2[256], fv = fc2[256];
        float2 ncv = { dv.x * cv.x + gac * fv.x, dv.y * cv.y + gac * fv.y };
        nc2[256] = ncv;
        float dx = ncv.x - cv.x, dy = ncv.y - cv.y;
        sdc += dx * dx + dy * dy;
        snc += ncv.x * ncv.x + ncv.y * ncv.y;
        float2 tv = t2[256], gv = ft2[256];
        float2 ntv = { dv.x * tv.x + gat * gv.x, dv.y * tv.y + gat * gv.y };
        nt2[256] = ntv;
        dx = ntv.x - tv.x; dy = ntv.y - tv.y;
        sdt += dx * dx + dy * dy;
        snt += ntv.x * ntv.x + ntv.y * ntv.y;
    }
#pragma unroll
    for (int o = 1; o < 64; o <<= 1) {
        sdc += __shfl_xor(sdc, o, 64);
        snc += __shfl_xor(snc, o, 64);
        sdt += __shfl_xor(sdt, o, 64);
        snt += __shfl_xor(snt, o, 64);
    }
    if (lane == 0) {
        red[wave * 4 + 0] = sqrtf(sdc);
        red[wave * 4 + 1] = sqrtf(sdt);
        red[wave * 4 + 2] = snc;
        red[wave * 4 + 3] = snt;
    }
    __syncthreads();
    if (tid < 4)
        part[tid * 1024 + blockIdx.x] =
            red[0 * 4 + tid] + red[1 * 4 + tid] + red[2 * 4 + tid] + red[3 * 4 + tid];
}

// scal layout: [80..99]=scale_c [100..119]=scale_t [120..139]=write_flag [140]=done
__global__ __launch_bounds__(256)
void update2(const float* __restrict__ part, float* __restrict__ scal, int step)
{
    __shared__ float red[4];
    const int tid = threadIdx.x, lane = tid & 63, wave = tid >> 6;
    const float* pq = part + wave * 1024;
    float s = 0.f;
#pragma unroll
    for (int k = 0; k < 16; ++k) s += pq[lane + k * 64];
#pragma unroll
    for (int o = 1; o < 64; o <<= 1) s += __shfl_xor(s, o, 64);
    if (lane == 0) red[wave] = s;
    __syncthreads();
    if (tid == 0) {
        float dc = red[0] * (1.0f / 4096.0f);
        float dt = red[1] * (1.0f / 4096.0f);
        bool conv = (dc < 1e-3f) && (dt < 1e-3f);
        float done = scal[140];
        scal[120 + step] = (done != 0.f) ? 0.f : 1.f;
        float nrc = sqrtf(red[2]);
        float nrt = sqrtf(red[3]);
        scal[80 + step]  = conv ? 1.f : (nrc > 10.f ? 10.f / nrc : 1.f);
        scal[100 + step] = conv ? 1.f : (nrt > 10.f ? 10.f / nrt : 1.f);
        scal[140] = (done != 0.f || conv) ? 1.f : 0.f;
    }
}

__global__ __launch_bounds__(256)
void update3(float* __restrict__ c, float* __restrict__ t,
             const float* __restrict__ nc, const float* __restrict__ nt,
             bf16* __restrict__ X, bf16* __restrict__ Cb, bf16* __restrict__ Tb,
             const float* __restrict__ scal, int step)
{
    if (scal[120 + step] == 0.f) return;    // frozen after convergence
    const float sc = scal[80 + step], st = scal[100 + step];
    const int lane = threadIdx.x & 63, wave = threadIdx.x >> 6;
    const int row = blockIdx.x * 4 + wave;
    const float2* nc2 = (const float2*)(nc + (long)row * CLD);
    const float2* nt2 = (const float2*)(nt + (long)row * CLD);
    float2* c2 = (float2*)(c + (long)row * CLD);
    float2* t2 = (float2*)(t + (long)row * CLD);
    bf16* xr = X  + (long)row * XCT;
    bf16* cb = Cb + (long)row * KDP;
    bf16* tb = Tb + (long)row * KDP;
#pragma unroll
    for (int k = 0; k < 5; ++k) {
        int j = lane + k * 64;
        if (k == 4 && lane > 0) break;      // only f2 idx 256 in tail
        float2 cv = nc2[j]; cv.x *= sc; cv.y *= sc;
        float2 tv = nt2[j]; tv.x *= st; tv.y *= st;
        c2[j] = cv;
        t2[j] = tv;
        *(unsigned*)(xr + j * 2)       = packbf(cv.x, cv.y);
        *(unsigned*)(xr + 514 + j * 2) = packbf(tv.x, tv.y);
        *(unsigned*)(cb + j * 2) = packbf(n2n(cv.x), n2n(cv.y));
        *(unsigned*)(tb + j * 2) = packbf(n2n(tv.x), n2n(tv.y));
    }
}

// ---------------- host ----------------
extern "C" void kernel_launch(void* const* d_in, const int* in_sizes, int n_in,
                              void* d_out, int out_size, void* d_ws, size_t ws_size,
                              hipStream_t stream)
{
    (void)in_sizes; (void)n_in; (void)out_size; (void)ws_size;
    const float* carrier = (const float*)d_in[0];
    const float* traj    = (const float*)d_in[1];
    const float* srcp    = (const float*)d_in[2];
    const float* tgtp    = (const float*)d_in[3];
    const float* cw1 = (const float*)d_in[4];  const float* cb1 = (const float*)d_in[5];
    const float* cg  = (const float*)d_in[6];  const float* cbe = (const float*)d_in[7];
    const float* cw2 = (const float*)d_in[8];  const float* cb2 = (const float*)d_in[9];
    const float* tw1 = (const float*)d_in[10]; const float* tb1 = (const float*)d_in[11];
    const float* tg  = (const float*)d_in[12]; const float* tbe = (const float*)d_in[13];
    const float* tw2 = (const float*)d_in[14]; const float* tb2 = (const float*)d_in[15];
    const float* fd  = (const float*)d_in[16];
    const float* dw1 = (const float*)d_in[17]; const float* db1 = (const float*)d_in[18];
    const float* dw2 = (const float*)d_in[19]; const float* db2 = (const float*)d_in[20];
    const float* sw1 = (const float*)d_in[21]; const float* sb1 = (const float*)d_in[22];
    const float* sw2 = (const float*)d_in[23]; const float* sb2 = (const float*)d_in[24];
    const float* csc = (const float*)d_in[25]; const float* tsc = (const float*)d_in[26];

    char* p = (char*)d_ws;
    size_t off = 0;
    auto take = [&](size_t bytes) { size_t o = off; off += (bytes + 255) & ~(size_t)255; return o; };
    bf16*  Xct  = (bf16*) (p + take((size_t)RTOT * XCT * 2));
    bf16*  W1ct = (bf16*) (p + take((size_t)NT1 * XCT * 2));
    float* Y    = (float*)(p + take((size_t)RTOT * NT1 * 4));
    bf16*  H    = (bf16*) (p + take((size_t)RTOT * HLD * 2));
    bf16*  W2t  = (bf16*) (p + take((size_t)1280 * KH * 2));
    bf16*  Wdc  = (bf16*) (p + take((size_t)NDC * KDP * 2));
    float* Ybase= (float*)(p + take((size_t)8 * NT1 * 4));
    float* b2c  = (float*)(p + take(1280 * 4));
    float* bdc  = (float*)(p + take(NDC * 4));
    float* RT   = (float*)(p + take(640L * 512 * 4));
    float* IT   = (float*)(p + take(512L * 640 * 4));
    float* damp = (float*)(p + take(F2E * 4));
    float* cbuf = (float*)(p + take((size_t)RTOT * CLD * 4));
    float* tbuf = (float*)(p + take((size_t)RTOT * CLD * 4));
    float* ncb  = (float*)(p + take((size_t)RTOT * CLD * 4));
    float* ntb  = (float*)(p + take((size_t)RTOT * CLD * 4));
    float* fcb  = (float*)(p + take((size_t)2 * RTOT * CLD * 4)); // [fc | ft] contiguous
    float* ftb  = fcb + (size_t)RTOT * CLD;
    bf16*  Cbb  = (bf16*) (p + take((size_t)2 * RTOT * KDP * 2)); // [Cb | Tb] contiguous
    bf16*  Tbb  = Cbb + (size_t)RTOT * KDP;
    float* Hd   = (float*)(p + take((size_t)2 * RTOT * NDC * 4)); // stacked c|t
    float* part = (float*)(p + take(4096 * 4));
    float* scal = (float*)(p + take(1024));

    hipMemsetAsync(scal, 0, 1024, stream);

    build_tables<<<2560, 256, 0, stream>>>(RT, IT);
    build_damp<<<3, 256, 0, stream>>>(damp, fd);
    ybase_build<<<dim3(8, 9), 256, 0, stream>>>(srcp, tgtp, cw1, cb1, tw1, tb1, Ybase);
    wprep<<<dim3(NT1, 5), 256, 0, stream>>>(W1ct, XCT, cw1, 1028, 1028, 0, tw1, 1028, 1028, 1152);
    wprep<<<dim3(1280, 5), 256, 0, stream>>>(W2t, KH, cw2, 1028, 514, 0, tw2, 1028, 514, 640);
    wprep<<<dim3(NDC, 3), 256, 0, stream>>>(Wdc, KDP, dw1, 514, 257, 0, sw1, 514, 128, 257);
    bias_fill<<<5, 256, 0, stream>>>(b2c, 1280, cb2, 514, 0, tb2, 514, 640);
    bias_fill<<<2, 256, 0, stream>>>(bdc, NDC, db1, 257, 0, sb1, 128, 257);
    xpad_zero<<<RTOT, 32, 0, stream>>>(Xct);

    // rfft (fp32 DFT-matmul); RT pad rows also zero the c/t pad columns
    sgemm_bt<<<dim3(64, 10), 256, 0, stream>>>(carrier, SP, RT, SP, cbuf, CLD, 32);
    sgemm_bt<<<dim3(64, 10), 256, 0, stream>>>(traj,    SP, RT, SP, tbuf, CLD, 32);
    initconv<<<RTOT, 256, 0, stream>>>(cbuf, tbuf, Xct, Cbb, Tbb);

    for (int s = 0; s < 20; ++s) {
        // GEMM1: [c,t] x W1ct^T + Ybase[batch]  (K halved via precomputed src/tgt part)
        gemm_bt<0><<<dim3(32, 18), 256, 0, stream>>>(Xct, XCT, W1ct, XCT, Y, NT1,
                                                     Ybase, NT1, 33, 0, 0, 0, 0);
        ln_gelu<<<2048, 256, 0, stream>>>(Y, H, cg, cbe, tg, tbe);
        // GEMM2 (both nets in one launch via z)
        gemm_bt<1><<<dim3(32, 5, 2), 256, 0, stream>>>(H, HLD, W2t, KH, fcb, CLD,
                                                       b2c, 0, 34,
                                                       (long)KH, (long)640 * KH,
                                                       (long)RTOT * CLD, 640);
        // small-MLP hidden for c and t branches in one stacked GEMM (M=8192)
        gemm_bt<2><<<dim3(64, 4), 256, 0, stream>>>(Cbb, KDP, Wdc, KDP, Hd, NDC,
                                                    bdc, 0, 18, 0, 0, 0, 0);
        fused_update<<<1024, 256, 0, stream>>>(Hd, dw2, db2, sw2, sb2,
                                               cbuf, tbuf, fcb, ftb, ncb, ntb,
                                               damp, csc, tsc, part);
        update2<<<1, 256, 0, stream>>>(part, scal, s);
        update3<<<1024, 256, 0, stream>>>(cbuf, tbuf, ncb, ntb, Xct, Cbb, Tbb, scal, s);
    }

    float* out = (float*)d_out;
    sgemm_bt<<<dim3(64, 8), 256, 0, stream>>>(cbuf, CLD, IT, CLD, out, SP, 40);
    sgemm_bt<<<dim3(64, 8), 256, 0, stream>>>(tbuf, CLD, IT, CLD, out + (size_t)RTOT * SP, SP, 40);
}

// Round 8
// 3133.216 us; speedup vs baseline: 1.8501x; 1.0024x over previous
//
#include <hip/hip_runtime.h>
#include <hip/hip_bf16.h>
#include <math.h>

typedef __hip_bfloat16 bf16;
using s16x8 = __attribute__((ext_vector_type(8))) short;
using f32x4 = __attribute__((ext_vector_type(4))) float;
typedef __attribute__((address_space(1))) const unsigned int gu32;
typedef __attribute__((address_space(3))) unsigned int lu32;

#define RTOT 4096      // B*S rows
#define XCT  1056      // c,t input stride (K1: 1028->1056, 33 BK32 tiles)
#define NT1  2176      // GEMM1 packed N (c cols 0..1027, t cols 1028..2055, pad ->2176)
#define HLD  2176      // H stride (2 nets x 1088)
#define KH   1088      // GEMM2 K padded (1028->1088)
#define CLD  640       // c/t/fc/nc fp32 stride
#define KDP  576       // small-mlp K padded (514->576)
#define NDC  512       // d+s hidden padded (257+128=385 -> 512)
#define F2E  514
#define SP   512
#define YZS  16        // ybase split-K factor

__device__ __forceinline__ float gelu_ex(float x) {
    return 0.5f * x * (1.0f + erff(x * 0.70710678118654752f));
}
__device__ __forceinline__ float sigm(float x) { return 1.0f / (1.0f + expf(-x)); }
__device__ __forceinline__ float n2n(float x) {
    if (isnan(x)) return 0.0f;
    if (isinf(x)) return x > 0.0f ? 1e6f : -1e6f;
    return x;
}
__device__ __forceinline__ unsigned short bfb(float x) {
    __hip_bfloat16 h = __float2bfloat16(x);
    return *(unsigned short*)&h;
}
__device__ __forceinline__ unsigned packbf(float x, float y) {
    return (unsigned)bfb(x) | ((unsigned)bfb(y) << 16);
}
__device__ __forceinline__ void glds16(const bf16* g, short* l) {
    __builtin_amdgcn_global_load_lds((gu32*)g, (lu32*)l, 16, 0, 0);
}

// ---------------- bf16 MFMA GEMM: C[M,N] = A[M,K] * Bt[N,K]^T (+bias, epilogue) ----
// m97 structure: global_load_lds width-16 staging, linear LDS, 2 barriers/K-step.
// EPI: 0 = x+bias, 1 = tanh(x+bias), 2 = gelu(x+bias)
// bias_ld != 0 -> 2D bias indexed by batch row (mb>>9). z-offsets allow merged launches.
template<int EPI>
__global__ __launch_bounds__(256)
void gemm_bt(const bf16* __restrict__ A, int lda,
             const bf16* __restrict__ Bt, int ldb,
             float* __restrict__ C, int ldc,
             const float* __restrict__ bias, int bias_ld, int ktiles,
             long zA, long zB, long zC, long zBias)
{
    A    += (long)blockIdx.z * zA;
    Bt   += (long)blockIdx.z * zB;
    C    += (long)blockIdx.z * zC;
    bias += (long)blockIdx.z * zBias;

    __shared__ __align__(16) short As[128 * 32];
    __shared__ __align__(16) short Bs[128 * 32];
    const int tid  = threadIdx.x;
    const int lane = tid & 63;
    const int wave = tid >> 6;
    const int l15  = lane & 15, kl = lane >> 4;
    const long mb = (long)blockIdx.x * 128;
    const long nb = (long)blockIdx.y * 128;
    const int wr = (wave >> 1) * 64;
    const int wc = (wave & 1) * 64;

    f32x4 acc[4][4] = {};

    // staging: wave w owns rows [w*32, w*32+32); 2 global_load_lds x 16 rows per operand.
    const int grp_r = lane >> 2;            // 0..15
    const int gcol  = (lane & 3) * 8;       // shorts
    const bf16* gA0 = A  + (mb + wave * 32 + grp_r) * (long)lda + gcol;
    const bf16* gA1 = gA0 + 16 * (long)lda;
    const bf16* gB0 = Bt + (nb + wave * 32 + grp_r) * (long)ldb + gcol;
    const bf16* gB1 = gB0 + 16 * (long)ldb;
    short* lA0 = &As[(wave * 32) * 32];
    short* lA1 = &As[(wave * 32 + 16) * 32];
    short* lB0 = &Bs[(wave * 32) * 32];
    short* lB1 = &Bs[(wave * 32 + 16) * 32];

    for (int kt = 0; kt < ktiles; ++kt) {
        const long ko = (long)kt * 32;
        __syncthreads();                 // prev iteration's LDS reads done
        glds16(gA0 + ko, lA0);
        glds16(gA1 + ko, lA1);
        glds16(gB0 + ko, lB0);
        glds16(gB1 + ko, lB1);
        __syncthreads();                 // compiler drains vmcnt before barrier
        s16x8 af[4], bfr[4];
#pragma unroll
        for (int m = 0; m < 4; ++m) {
            int ar = wr + m * 16 + l15;
            af[m] = *reinterpret_cast<const s16x8*>(&As[ar * 32 + kl * 8]);
        }
#pragma unroll
        for (int n = 0; n < 4; ++n) {
            int br = wc + n * 16 + l15;
            bfr[n] = *reinterpret_cast<const s16x8*>(&Bs[br * 32 + kl * 8]);
        }
#pragma unroll
        for (int m = 0; m < 4; ++m)
#pragma unroll
            for (int n = 0; n < 4; ++n)
                acc[m][n] = __builtin_amdgcn_mfma_f32_16x16x32_bf16(af[m], bfr[n], acc[m][n], 0, 0, 0);
    }

    const float* brow = bias + (bias_ld ? (long)(mb >> 9) * bias_ld : 0);
#pragma unroll
    for (int m = 0; m < 4; ++m) {
        const long grow0 = mb + wr + m * 16 + kl * 4;
#pragma unroll
        for (int n = 0; n < 4; ++n) {
            const long gcol2 = nb + wc + n * 16 + l15;
            const float bb = brow[gcol2];
            f32x4 v = acc[m][n];
#pragma unroll
            for (int r = 0; r < 4; ++r) {
                float x = v[r] + bb;
                if (EPI == 1) x = tanhf(x);
                else if (EPI == 2) x = gelu_ex(x);
                C[(grow0 + r) * (long)ldc + gcol2] = x;
            }
        }
    }
}

// ---------------- fp32 SGEMM (rfft/irfft tables): C[M,N] = A[M,K] * Bt[N,K]^T -------
__global__ __launch_bounds__(256)
void sgemm_bt(const float* __restrict__ A, int lda,
              const float* __restrict__ Bt, int ldb,
              float* __restrict__ C, int ldc, int ktiles)
{
    __shared__ float As[16][68];   // [k][m], 68 = 64 + 4 pad
    __shared__ float Bs[16][68];   // [k][n]
    const int tid = threadIdx.x;
    const int tx = tid & 15, ty = tid >> 4;
    const int lr = tid >> 2, lc = (tid & 3) * 4;     // load: row 0..63, col 4-chunk
    const long mb = (long)blockIdx.x * 64, nb = (long)blockIdx.y * 64;
    float acc[4][4] = {};
    const float* Ap = A  + (mb + lr) * (long)lda + lc;
    const float* Bp = Bt + (nb + lr) * (long)ldb + lc;
    for (int kt = 0; kt < ktiles; ++kt) {
        float4 av = *(const float4*)(Ap + kt * 16);
        float4 bv = *(const float4*)(Bp + kt * 16);
        __syncthreads();
        As[lc + 0][lr] = av.x; As[lc + 1][lr] = av.y;
        As[lc + 2][lr] = av.z; As[lc + 3][lr] = av.w;
        Bs[lc + 0][lr] = bv.x; Bs[lc + 1][lr] = bv.y;
        Bs[lc + 2][lr] = bv.z; Bs[lc + 3][lr] = bv.w;
        __syncthreads();
#pragma unroll
        for (int kk = 0; kk < 16; ++kk) {
            float4 a = *(const float4*)&As[kk][ty * 4];
            float4 b = *(const float4*)&Bs[kk][tx * 4];
            acc[0][0] = fmaf(a.x, b.x, acc[0][0]); acc[0][1] = fmaf(a.x, b.y, acc[0][1]);
            acc[0][2] = fmaf(a.x, b.z, acc[0][2]); acc[0][3] = fmaf(a.x, b.w, acc[0][3]);
            acc[1][0] = fmaf(a.y, b.x, acc[1][0]); acc[1][1] = fmaf(a.y, b.y, acc[1][1]);
            acc[1][2] = fmaf(a.y, b.z, acc[1][2]); acc[1][3] = fmaf(a.y, b.w, acc[1][3]);
            acc[2][0] = fmaf(a.z, b.x, acc[2][0]); acc[2][1] = fmaf(a.z, b.y, acc[2][1]);
            acc[2][2] = fmaf(a.z, b.z, acc[2][2]); acc[2][3] = fmaf(a.z, b.w, acc[2][3]);
            acc[3][0] = fmaf(a.w, b.x, acc[3][0]); acc[3][1] = fmaf(a.w, b.y, acc[3][1]);
            acc[3][2] = fmaf(a.w, b.z, acc[3][2]); acc[3][3] = fmaf(a.w, b.w, acc[3][3]);
        }
    }
#pragma unroll
    for (int i = 0; i < 4; ++i) {
        float4 st = { acc[i][0], acc[i][1], acc[i][2], acc[i][3] };
        *(float4*)&C[(mb + ty * 4 + i) * (long)ldc + nb + tx * 4] = st;
    }
}

// ---------------- setup kernels ----------------
__global__ void build_tables(float* __restrict__ RT, float* __restrict__ IT)
{
    long idx = (long)blockIdx.x * 256 + threadIdx.x;
    const double W = 6.283185307179586476925286766559005768 / 512.0;
    if (idx < 640L * 512) {                  // RT[640][512]: rfft rows (re/im interleaved)
        int r = (int)(idx >> 9), n = (int)(idx & 511);
        float v = 0.f;
        if (r < F2E) {
            int bin = r >> 1;
            int m = (bin * n) & 511;
            double ang = W * m;
            v = (r & 1) ? (float)(-sin(ang)) : (float)cos(ang);
        }
        RT[idx] = v;
    } else {
        long j2 = idx - 640L * 512;          // IT[512][640]: irfft rows
        if (j2 < 512L * 640) {
            int n = (int)(j2 / 640), j = (int)(j2 % 640);
            float v = 0.f;
            if (j < F2E) {
                int bin = j >> 1;
                int m = (bin * n) & 511;
                double ang = W * m;
                bool edge = (bin == 0 || bin == 256);
                double ck = edge ? 1.0 : 2.0;
                if (j & 1) v = edge ? 0.f : (float)(-ck * sin(ang) / 512.0);
                else       v = (float)(ck * cos(ang) / 512.0);
            }
            IT[j2] = v;
        }
    }
}

__global__ void build_damp(float* damp, const float* __restrict__ fd)
{
    int i = blockIdx.x * 256 + threadIdx.x;
    if (i < F2E) damp[i] = fd[i < 257 ? i : i - 257];   // torch repeat(...,2) tiling quirk
}

// split-K ybase partials: Yp[z][b][n] = sum_{k in chunk z} src[b][k]*W1[1028+k][n] + tgt[b][k]*W1[1540+k][n]
// grid (NT1/256=9 ceil, 8, YZS); packed n: c-net [0,1028), t-net [1028,2056), pad 0.
__global__ void ybase_part(const float* __restrict__ srcp, const float* __restrict__ tgtp,
                           const float* __restrict__ cw1, const float* __restrict__ tw1,
                           float* __restrict__ Yp)
{
    const int n = blockIdx.x * 256 + threadIdx.x;
    const int b = blockIdx.y, z = blockIdx.z;
    if (n >= NT1) return;
    float acc = 0.f;
    if (n < 2056) {
        const bool isT = (n >= 1028);
        const int nn = isT ? n - 1028 : n;
        const float* w = isT ? tw1 : cw1;
        const float* s = srcp + b * 513;
        const float* t = tgtp + b * 513;
        const int k0 = z * (512 / YZS);
        for (int k = k0; k < k0 + 512 / YZS; ++k) {
            acc = fmaf(s[k], w[(size_t)(1028 + k) * 1028 + nn], acc);
            acc = fmaf(t[k], w[(size_t)(1540 + k) * 1028 + nn], acc);
        }
    }
    Yp[((size_t)z * 8 + b) * NT1 + n] = acc;
}

// Ybase[b][n] = bias1[n] + sum_z Yp[z][b][n]
__global__ void ybase_reduce(const float* __restrict__ Yp,
                             const float* __restrict__ cb1, const float* __restrict__ tb1,
                             float* __restrict__ Yb)
{
    const int n = blockIdx.x * 256 + threadIdx.x;
    const int b = blockIdx.y;
    if (n >= NT1) return;
    float acc = 0.f;
    if (n < 2056) acc = (n < 1028) ? cb1[n] : tb1[n - 1028];
    for (int z = 0; z < YZS; ++z) acc += Yp[((size_t)z * 8 + b) * NT1 + n];
    Yb[b * NT1 + n] = acc;
}

// transpose fp32 [K,N] weights into bf16 [rows=ldn][cols=ldk], zero-padded, 2 segments
__global__ void wprep(bf16* __restrict__ dst, int ldk,
                      const float* s0, int K0, int N0, int r00,
                      const float* s1, int K1, int N1, int r01)
{
    int r = blockIdx.x;
    int k = blockIdx.y * 256 + threadIdx.x;
    if (k >= ldk) return;
    float v = 0.f;
    if (s0 && r >= r00 && r < r00 + N0 && k < K0) v = s0[(long)k * N0 + (r - r00)];
    if (s1 && r >= r01 && r < r01 + N1 && k < K1) v = s1[(long)k * N1 + (r - r01)];
    dst[(long)r * ldk + k] = __float2bfloat16(v);
}

__global__ void bias_fill(float* __restrict__ dst, int n,
                          const float* s0, int l0, int o0,
                          const float* s1, int l1, int o1)
{
    int i = blockIdx.x * 256 + threadIdx.x;
    if (i >= n) return;
    float v = 0.f;
    if (s0 && i >= o0 && i < o0 + l0) v = s0[i - o0];
    if (s1 && i >= o1 && i < o1 + l1) v = s1[i - o1];
    dst[i] = v;
}

__global__ void initconv(const float* __restrict__ cb, const float* __restrict__ tb,
                         bf16* __restrict__ X, bf16* __restrict__ Cb, bf16* __restrict__ Tb)
{
    int row = blockIdx.x;
    for (int j = threadIdx.x; j < F2E; j += 256) {
        float cv = cb[(long)row * CLD + j], tv = tb[(long)row * CLD + j];
        X[(long)row * XCT + j]        = __float2bfloat16(cv);
        X[(long)row * XCT + 514 + j]  = __float2bfloat16(tv);
        Cb[(long)row * KDP + j] = __float2bfloat16(n2n(cv));
        Tb[(long)row * KDP + j] = __float2bfloat16(n2n(tv));
    }
}

// zero the K-pad columns of Xct once (pads never rewritten afterwards)
__global__ void xpad_zero(bf16* __restrict__ X)
{
    int row = blockIdx.x;
    int j = 1028 + threadIdx.x;          // 28 pad cols, 32 threads
    if (j < XCT) X[(long)row * XCT + j] = __float2bfloat16(0.f);
}

// ---------------- per-step kernels (wave-per-row, vectorized) ----------------
__global__ __launch_bounds__(256)
void ln_gelu(const float* __restrict__ Y, bf16* __restrict__ H,
             const float* __restrict__ cg, const float* __restrict__ cbeta,
             const float* __restrict__ tg, const float* __restrict__ tbeta)
{
    const int lane = threadIdx.x & 63, wave = threadIdx.x >> 6;
    const int p = blockIdx.x * 4 + wave;      // 8192 (row,net) pairs
    const int row = p >> 1, net = p & 1;
    const float4* y4 = (const float4*)(Y + (long)row * NT1 + net * 1028);
    float4 v[4], vt = {0.f, 0.f, 0.f, 0.f};
    float s = 0.f;
#pragma unroll
    for (int k = 0; k < 4; ++k) {
        v[k] = y4[lane + k * 64];
        s += v[k].x + v[k].y + v[k].z + v[k].w;
    }
    if (lane == 0) { vt = y4[256]; s += vt.x + vt.y + vt.z + vt.w; }
#pragma unroll
    for (int o = 1; o < 64; o <<= 1) s += __shfl_xor(s, o, 64);
    const float mean = s * (1.0f / 1028.0f);
    float vs = 0.f;
#pragma unroll
    for (int k = 0; k < 4; ++k) {
        float a = v[k].x - mean, b = v[k].y - mean, c = v[k].z - mean, d = v[k].w - mean;
        vs += a * a + b * b + c * c + d * d;
    }
    if (lane == 0) {
        float a = vt.x - mean, b = vt.y - mean, c = vt.z - mean, d = vt.w - mean;
        vs += a * a + b * b + c * c + d * d;
    }
#pragma unroll
    for (int o = 1; o < 64; o <<= 1) vs += __shfl_xor(vs, o, 64);
    const float rs = rsqrtf(vs * (1.0f / 1028.0f) + 1e-5f);
    const float4* g4 = (const float4*)(net ? tg : cg);
    const float4* b4 = (const float4*)(net ? tbeta : cbeta);
    bf16* h = H + (long)row * HLD + (long)net * KH;
#pragma unroll
    for (int k = 0; k < 4; ++k) {
        int j = lane + k * 64;
        float4 gv = g4[j], bv = b4[j];
        ushort4 o;
        o.x = bfb(gelu_ex((v[k].x - mean) * rs * gv.x + bv.x));
        o.y = bfb(gelu_ex((v[k].y - mean) * rs * gv.y + bv.y));
        o.z = bfb(gelu_ex((v[k].z - mean) * rs * gv.z + bv.z));
        o.w = bfb(gelu_ex((v[k].w - mean) * rs * gv.w + bv.w));
        *(ushort4*)(&h[j * 4]) = o;
    }
    if (lane == 0) {
        float4 gv = g4[256], bv = b4[256];
        ushort4 o;
        o.x = bfb(gelu_ex((vt.x - mean) * rs * gv.x + bv.x));
        o.y = bfb(gelu_ex((vt.y - mean) * rs * gv.y + bv.y));
        o.z = bfb(gelu_ex((vt.z - mean) * rs * gv.z + bv.z));
        o.w = bfb(gelu_ex((vt.w - mean) * rs * gv.w + bv.w));
        *(ushort4*)(&h[1024]) = o;
    }
}

// fused heads + state update; per-block partials (NO atomics).
// Hd stacked: rows 0..4095 = c-branch, rows 4096..8191 = t-branch.
// part layout: part[q*1024 + block], q: 0=sum sqrt(dc), 1=sum sqrt(dt), 2=sum nc^2, 3=sum nt^2
__global__ __launch_bounds__(256)
void fused_update(const float* __restrict__ Hd,
                  const float* __restrict__ dw2, const float* __restrict__ db2,
                  const float* __restrict__ sw2, const float* __restrict__ sb2,
                  const float* __restrict__ c, const float* __restrict__ t,
                  const float* __restrict__ fc, const float* __restrict__ ft,
                  float* __restrict__ nc, float* __restrict__ nt,
                  const float* __restrict__ damp,
                  const float* __restrict__ csc, const float* __restrict__ tsc,
                  float* __restrict__ part)
{
    __shared__ float red[16];
    const int tid = threadIdx.x, lane = tid & 63, wave = tid >> 6;
    const int row = blockIdx.x * 4 + wave;

    // --- heads: alpha_c, alpha_t, gamma for this row ---
    const float* hc = Hd + (long)row * NDC;
    const float* ht = Hd + (long)(4096 + row) * NDC;
    float s1 = 0.f, s2 = 0.f, s3 = 0.f;
#pragma unroll
    for (int k = 0; k < 4; ++k) {
        int j = lane + k * 64;
        s1 += hc[j] * dw2[j];
        s3 += ht[j] * dw2[j];
    }
    if (lane == 0) { s1 += hc[256] * dw2[256]; s3 += ht[256] * dw2[256]; }
#pragma unroll
    for (int k = 0; k < 2; ++k) {
        int j = lane + k * 64;
        s2 += hc[257 + j] * sw2[j];
    }
#pragma unroll
    for (int o = 1; o < 64; o <<= 1) {
        s1 += __shfl_xor(s1, o, 64);
        s2 += __shfl_xor(s2, o, 64);
        s3 += __shfl_xor(s3, o, 64);
    }
    float a  = sigm(s1 + db2[0]);
    float at = sigm(s3 + db2[0]);
    float g  = sigm(s2 + sb2[0]) + 0.5f;
    if (isnan(a))  a  = 0.f;
    if (isnan(at)) at = 0.f;
    const float gac = g * a  * csc[0];
    const float gat = g * at * tsc[0];

    // --- damp update + norms (float2, 257 f2 per row) ---
    const float2* c2  = (const float2*)(c  + (long)row * CLD);
    const float2* t2  = (const float2*)(t  + (long)row * CLD);
    const float2* fc2 = (const float2*)(fc + (long)row * CLD);
    const float2* ft2 = (const float2*)(ft + (long)row * CLD);
    float2* nc2 = (float2*)(nc + (long)row * CLD);
    float2* nt2 = (float2*)(nt + (long)row * CLD);
    const float2* d2 = (const float2*)damp;
    float sdc = 0.f, snc = 0.f, sdt = 0.f, snt = 0.f;
#pragma unroll
    for (int k = 0; k < 4; ++k) {
        int j = lane + k * 64;
        float2 dv = d2[j];
        float2 cv = c2[j], fv = fc2[j];
        float2 ncv = { dv.x * cv.x + gac * fv.x, dv.y * cv.y + gac * fv.y };
        nc2[j] = ncv;
        float dx = ncv.x - cv.x, dy = ncv.y - cv.y;
        sdc += dx * dx + dy * dy;
        snc += ncv.x * ncv.x + ncv.y * ncv.y;
        float2 tv = t2[j], gv = ft2[j];
        float2 ntv = { dv.x * tv.x + gat * gv.x, dv.y * tv.y + gat * gv.y };
        nt2[j] = ntv;
        dx = ntv.x - tv.x; dy = ntv.y - tv.y;
        sdt += dx * dx + dy * dy;
        snt += ntv.x * ntv.x + ntv.y * ntv.y;
    }
    if (lane == 0) {    // tail f2 index 256 (elements 512,513)
        float2 dv = d2[256];
        float2 cv = c2[256], fv = fc2[256];
        float2 ncv = { dv.x * cv.x + gac * fv.x, dv.y * cv.y + gac * fv.y };
        nc2[256] = ncv;
        float dx = ncv.x - cv.x, dy = ncv.y - cv.y;
        sdc += dx * dx + dy * dy;
        snc += ncv.x * ncv.x + ncv.y * ncv.y;
        float2 tv = t2[256], gv = ft2[256];
        float2 ntv = { dv.x * tv.x + gat * gv.x, dv.y * tv.y + gat * gv.y };
        nt2[256] = ntv;
        dx = ntv.x - tv.x; dy = ntv.y - tv.y;
        sdt += dx * dx + dy * dy;
        snt += ntv.x * ntv.x + ntv.y * ntv.y;
    }
#pragma unroll
    for (int o = 1; o < 64; o <<= 1) {
        sdc += __shfl_xor(sdc, o, 64);
        snc += __shfl_xor(snc, o, 64);
        sdt += __shfl_xor(sdt, o, 64);
        snt += __shfl_xor(snt, o, 64);
    }
    if (lane == 0) {
        red[wave * 4 + 0] = sqrtf(sdc);
        red[wave * 4 + 1] = sqrtf(sdt);
        red[wave * 4 + 2] = snc;
        red[wave * 4 + 3] = snt;
    }
    __syncthreads();
    if (tid < 4)
        part[tid * 1024 + blockIdx.x] =
            red[0 * 4 + tid] + red[1 * 4 + tid] + red[2 * 4 + tid] + red[3 * 4 + tid];
}

// update3 with fused convergence logic (update2 eliminated).
// done-flag double-buffered by step: read scal[step], block 0 writes scal[step+1].
// Each block redundantly reduces part[4][1024] (identical result in every block).
__global__ __launch_bounds__(256)
void update3(float* __restrict__ c, float* __restrict__ t,
             const float* __restrict__ nc, const float* __restrict__ nt,
             bf16* __restrict__ X, bf16* __restrict__ Cb, bf16* __restrict__ Tb,
             const float* __restrict__ part, float* __restrict__ scal, int step)
{
    __shared__ float red[4];
    const int tid = threadIdx.x, lane = tid & 63, wave = tid >> 6;
    {
        const float* pq = part + wave * 1024;
        float s = 0.f;
#pragma unroll
        for (int k = 0; k < 16; ++k) s += pq[lane + k * 64];
#pragma unroll
        for (int o = 1; o < 64; o <<= 1) s += __shfl_xor(s, o, 64);
        if (lane == 0) red[wave] = s;
    }
    __syncthreads();
    const float done = scal[step];
    const float dc = red[0] * (1.0f / 4096.0f);
    const float dt = red[1] * (1.0f / 4096.0f);
    const bool conv = (dc < 1e-3f) && (dt < 1e-3f);
    if (blockIdx.x == 0 && tid == 0)
        scal[step + 1] = (done != 0.f || conv) ? 1.f : 0.f;
    if (done != 0.f) return;               // frozen after convergence
    const float nrc = sqrtf(red[2]);
    const float nrt = sqrtf(red[3]);
    const float sc = conv ? 1.f : (nrc > 10.f ? 10.f / nrc : 1.f);
    const float st = conv ? 1.f : (nrt > 10.f ? 10.f / nrt : 1.f);

    const int row = blockIdx.x * 4 + wave;
    const float2* nc2 = (const float2*)(nc + (long)row * CLD);
    const float2* nt2 = (const float2*)(nt + (long)row * CLD);
    float2* c2 = (float2*)(c + (long)row * CLD);
    float2* t2 = (float2*)(t + (long)row * CLD);
    bf16* xr = X  + (long)row * XCT;
    bf16* cb = Cb + (long)row * KDP;
    bf16* tb = Tb + (long)row * KDP;
#pragma unroll
    for (int k = 0; k < 5; ++k) {
        int j = lane + k * 64;
        if (k == 4 && lane > 0) break;      // only f2 idx 256 in tail
        float2 cv = nc2[j]; cv.x *= sc; cv.y *= sc;
        float2 tv = nt2[j]; tv.x *= st; tv.y *= st;
        c2[j] = cv;
        t2[j] = tv;
        *(unsigned*)(xr + j * 2)       = packbf(cv.x, cv.y);
        *(unsigned*)(xr + 514 + j * 2) = packbf(tv.x, tv.y);
        *(unsigned*)(cb + j * 2) = packbf(n2n(cv.x), n2n(cv.y));
        *(unsigned*)(tb + j * 2) = packbf(n2n(tv.x), n2n(tv.y));
    }
}

// ---------------- host ----------------
extern "C" void kernel_launch(void* const* d_in, const int* in_sizes, int n_in,
                              void* d_out, int out_size, void* d_ws, size_t ws_size,
                              hipStream_t stream)
{
    (void)in_sizes; (void)n_in; (void)out_size; (void)ws_size;
    const float* carrier = (const float*)d_in[0];
    const float* traj    = (const float*)d_in[1];
    const float* srcp    = (const float*)d_in[2];
    const float* tgtp    = (const float*)d_in[3];
    const float* cw1 = (const float*)d_in[4];  const float* cb1 = (const float*)d_in[5];
    const float* cg  = (const float*)d_in[6];  const float* cbe = (const float*)d_in[7];
    const float* cw2 = (const float*)d_in[8];  const float* cb2 = (const float*)d_in[9];
    const float* tw1 = (const float*)d_in[10]; const float* tb1 = (const float*)d_in[11];
    const float* tg  = (const float*)d_in[12]; const float* tbe = (const float*)d_in[13];
    const float* tw2 = (const float*)d_in[14]; const float* tb2 = (const float*)d_in[15];
    const float* fd  = (const float*)d_in[16];
    const float* dw1 = (const float*)d_in[17]; const float* db1 = (const float*)d_in[18];
    const float* dw2 = (const float*)d_in[19]; const float* db2 = (const float*)d_in[20];
    const float* sw1 = (const float*)d_in[21]; const float* sb1 = (const float*)d_in[22];
    const float* sw2 = (const float*)d_in[23]; const float* sb2 = (const float*)d_in[24];
    const float* csc = (const float*)d_in[25]; const float* tsc = (const float*)d_in[26];

    char* p = (char*)d_ws;
    size_t off = 0;
    auto take = [&](size_t bytes) { size_t o = off; off += (bytes + 255) & ~(size_t)255; return o; };
    bf16*  Xct  = (bf16*) (p + take((size_t)RTOT * XCT * 2));
    bf16*  W1ct = (bf16*) (p + take((size_t)NT1 * XCT * 2));
    float* Y    = (float*)(p + take((size_t)RTOT * NT1 * 4));
    bf16*  H    = (bf16*) (p + take((size_t)RTOT * HLD * 2));
    bf16*  W2t  = (bf16*) (p + take((size_t)1280 * KH * 2));
    bf16*  Wdc  = (bf16*) (p + take((size_t)NDC * KDP * 2));
    float* Ybase= (float*)(p + take((size_t)8 * NT1 * 4));
    float* Ypart= (float*)(p + take((size_t)YZS * 8 * NT1 * 4));
    float* b2c  = (float*)(p + take(1280 * 4));
    float* bdc  = (float*)(p + take(NDC * 4));
    float* RT   = (float*)(p + take(640L * 512 * 4));
    float* IT   = (float*)(p + take(512L * 640 * 4));
    float* damp = (float*)(p + take(F2E * 4));
    float* cbuf = (float*)(p + take((size_t)RTOT * CLD * 4));
    float* tbuf = (float*)(p + take((size_t)RTOT * CLD * 4));
    float* ncb  = (float*)(p + take((size_t)RTOT * CLD * 4));
    float* ntb  = (float*)(p + take((size_t)RTOT * CLD * 4));
    float* fcb  = (float*)(p + take((size_t)2 * RTOT * CLD * 4)); // [fc | ft] contiguous
    float* ftb  = fcb + (size_t)RTOT * CLD;
    bf16*  Cbb  = (bf16*) (p + take((size_t)2 * RTOT * KDP * 2)); // [Cb | Tb] contiguous
    bf16*  Tbb  = Cbb + (size_t)RTOT * KDP;
    float* Hd   = (float*)(p + take((size_t)2 * RTOT * NDC * 4)); // stacked c|t
    float* part = (float*)(p + take(4096 * 4));
    float* scal = (float*)(p + take(1024));

    hipMemsetAsync(scal, 0, 1024, stream);      // scal[0] = done flag for step 0

    build_tables<<<2560, 256, 0, stream>>>(RT, IT);
    build_damp<<<3, 256, 0, stream>>>(damp, fd);
    ybase_part<<<dim3(9, 8, YZS), 256, 0, stream>>>(srcp, tgtp, cw1, tw1, Ypart);
    ybase_reduce<<<dim3(9, 8), 256, 0, stream>>>(Ypart, cb1, tb1, Ybase);
    wprep<<<dim3(NT1, 5), 256, 0, stream>>>(W1ct, XCT, cw1, 1028, 1028, 0, tw1, 1028, 1028, 1028);
    wprep<<<dim3(1280, 5), 256, 0, stream>>>(W2t, KH, cw2, 1028, 514, 0, tw2, 1028, 514, 640);
    wprep<<<dim3(NDC, 3), 256, 0, stream>>>(Wdc, KDP, dw1, 514, 257, 0, sw1, 514, 128, 257);
    bias_fill<<<5, 256, 0, stream>>>(b2c, 1280, cb2, 514, 0, tb2, 514, 640);
    bias_fill<<<2, 256, 0, stream>>>(bdc, NDC, db1, 257, 0, sb1, 128, 257);
    xpad_zero<<<RTOT, 32, 0, stream>>>(Xct);

    // rfft (fp32 DFT-matmul); RT pad rows also zero the c/t pad columns
    sgemm_bt<<<dim3(64, 10), 256, 0, stream>>>(carrier, SP, RT, SP, cbuf, CLD, 32);
    sgemm_bt<<<dim3(64, 10), 256, 0, stream>>>(traj,    SP, RT, SP, tbuf, CLD, 32);
    initconv<<<RTOT, 256, 0, stream>>>(cbuf, tbuf, Xct, Cbb, Tbb);

    for (int s = 0; s < 20; ++s) {
        // GEMM1: [c,t] x W1ct^T + Ybase[batch]  (packed N=2176, K halved via Ybase)
        gemm_bt<0><<<dim3(32, 17), 256, 0, stream>>>(Xct, XCT, W1ct, XCT, Y, NT1,
                                                     Ybase, NT1, 33, 0, 0, 0, 0);
        ln_gelu<<<2048, 256, 0, stream>>>(Y, H, cg, cbe, tg, tbe);
        // GEMM2 (both nets in one launch via z)
        gemm_bt<1><<<dim3(32, 5, 2), 256, 0, stream>>>(H, HLD, W2t, KH, fcb, CLD,
                                                       b2c, 0, 34,
                                                       (long)KH, (long)640 * KH,
                                                       (long)RTOT * CLD, 640);
        // small-MLP hidden for c and t branches in one stacked GEMM (M=8192)
        gemm_bt<2><<<dim3(64, 4), 256, 0, stream>>>(Cbb, KDP, Wdc, KDP, Hd, NDC,
                                                    bdc, 0, 18, 0, 0, 0, 0);
        fused_update<<<1024, 256, 0, stream>>>(Hd, dw2, db2, sw2, sb2,
                                               cbuf, tbuf, fcb, ftb, ncb, ntb,
                                               damp, csc, tsc, part);
        update3<<<1024, 256, 0, stream>>>(cbuf, tbuf, ncb, ntb, Xct, Cbb, Tbb,
                                          part, scal, s);
    }

    float* out = (float*)d_out;
    sgemm_bt<<<dim3(64, 8), 256, 0, stream>>>(cbuf, CLD, IT, CLD, out, SP, 40);
    sgemm_bt<<<dim3(64, 8), 256, 0, stream>>>(tbuf, CLD, IT, CLD, out + (size_t)RTOT * SP, SP, 40);
}

// Round 9
// 2692.322 us; speedup vs baseline: 2.1530x; 1.1638x over previous
//
#include <hip/hip_runtime.h>
#include <hip/hip_bf16.h>
#include <math.h>

typedef __hip_bfloat16 bf16;
using s16x8 = __attribute__((ext_vector_type(8))) short;
using f32x4 = __attribute__((ext_vector_type(4))) float;
typedef __attribute__((address_space(1))) const unsigned int gu32;
typedef __attribute__((address_space(3))) unsigned int lu32;

#define RTOT 4096      // B*S rows
#define XCT  1056      // c,t input stride (K1: 1028->1056, 33 BK32 tiles)
#define NT1  2176      // GEMM1 packed N (c cols 0..1027, t cols 1028..2055, pad ->2176)
#define HLD  2176      // H stride (2 nets x 1088)
#define KH   1088      // GEMM2 K padded (1028->1088)
#define CLD  640       // c/t/fc/nc fp32 stride
#define KDP  576       // small-mlp K padded (514->576)
#define NDC  512       // d+s hidden padded (257+128=385 -> 512)
#define F2E  514
#define SP   512
#define YZS  16        // ybase split-K factor

__device__ __forceinline__ float gelu_ex(float x) {
    return 0.5f * x * (1.0f + erff(x * 0.70710678118654752f));
}
__device__ __forceinline__ float sigm(float x) { return 1.0f / (1.0f + expf(-x)); }
__device__ __forceinline__ float n2n(float x) {
    if (isnan(x)) return 0.0f;
    if (isinf(x)) return x > 0.0f ? 1e6f : -1e6f;
    return x;
}
__device__ __forceinline__ unsigned short bfb(float x) {
    __hip_bfloat16 h = __float2bfloat16(x);
    return *(unsigned short*)&h;
}
__device__ __forceinline__ unsigned packbf(float x, float y) {
    return (unsigned)bfb(x) | ((unsigned)bfb(y) << 16);
}
__device__ __forceinline__ void glds16(const bf16* g, short* l) {
    __builtin_amdgcn_global_load_lds((gu32*)g, (lu32*)l, 16, 0, 0);
}

// ---------------- bf16 MFMA GEMM: C[M,N] = A[M,K] * Bt[N,K]^T (+bias, epilogue) ----
// 2-phase double-buffered staging (T3 minimum): issue next tile's global_load_lds
// BEFORE computing current tile; one __syncthreads per K-step (its vmcnt(0) drain
// fences both the prefetch and the barrier). Critical at 1-2 blocks/CU occupancy.
// BNT: 128 (gemm1) or 64 (gemm2/gemmd -> 2x block count for occupancy).
// EPI: 0 = x+bias, 1 = tanh(x+bias), 2 = gelu(x+bias)
template<int EPI, int BNT>
__global__ __launch_bounds__(256)
void gemm_bt(const bf16* __restrict__ A, int lda,
             const bf16* __restrict__ Bt, int ldb,
             float* __restrict__ C, int ldc,
             const float* __restrict__ bias, int bias_ld, int ktiles,
             long zA, long zB, long zC, long zBias)
{
    A    += (long)blockIdx.z * zA;
    Bt   += (long)blockIdx.z * zB;
    C    += (long)blockIdx.z * zC;
    bias += (long)blockIdx.z * zBias;

    constexpr int NC = BNT / 32;            // n-frags per wave (4 or 2)
    __shared__ __align__(16) short As[2][128 * 32];
    __shared__ __align__(16) short Bs[2][BNT * 32];
    const int tid  = threadIdx.x;
    const int lane = tid & 63;
    const int wave = tid >> 6;
    const int l15  = lane & 15, kl = lane >> 4;
    const long mb = (long)blockIdx.x * 128;
    const long nb = (long)blockIdx.y * BNT;
    const int wr = (wave >> 1) * 64;
    const int wc = (wave & 1) * (BNT / 2);

    f32x4 acc[4][NC] = {};

    // staging: each glds16 covers 16 rows (64 lanes x 16B). A: 8 total (2/wave).
    // B: BNT/16 total (2/wave at BNT=128, 1/wave at BNT=64).
    const int grp_r = lane >> 2;            // 0..15
    const int gcol  = (lane & 3) * 8;       // shorts
    const bf16* gA0 = A  + (mb + wave * 32 + grp_r) * (long)lda + gcol;
    const bf16* gA1 = gA0 + 16 * (long)lda;
    const int brow0 = (BNT == 128) ? wave * 32 : wave * 16;
    const bf16* gB0 = Bt + (nb + brow0 + grp_r) * (long)ldb + gcol;
    const bf16* gB1 = gB0 + 16 * (long)ldb;  // only used when BNT==128

    auto stage = [&](int buf, int kt) {
        const long ko = (long)kt * 32;
        glds16(gA0 + ko, &As[buf][(wave * 32) * 32]);
        glds16(gA1 + ko, &As[buf][(wave * 32 + 16) * 32]);
        glds16(gB0 + ko, &Bs[buf][brow0 * 32]);
        if (BNT == 128) glds16(gB1 + ko, &Bs[buf][(brow0 + 16) * 32]);
    };

    stage(0, 0);
    __syncthreads();                        // prologue drain
    int cur = 0;
    for (int kt = 0; kt < ktiles; ++kt) {
        if (kt + 1 < ktiles) stage(cur ^ 1, kt + 1);   // prefetch flies under compute
        s16x8 af[4], bfr[NC];
#pragma unroll
        for (int m = 0; m < 4; ++m) {
            int ar = wr + m * 16 + l15;
            af[m] = *reinterpret_cast<const s16x8*>(&As[cur][ar * 32 + kl * 8]);
        }
#pragma unroll
        for (int n = 0; n < NC; ++n) {
            int br = wc + n * 16 + l15;
            bfr[n] = *reinterpret_cast<const s16x8*>(&Bs[cur][br * 32 + kl * 8]);
        }
#pragma unroll
        for (int m = 0; m < 4; ++m)
#pragma unroll
            for (int n = 0; n < NC; ++n)
                acc[m][n] = __builtin_amdgcn_mfma_f32_16x16x32_bf16(af[m], bfr[n], acc[m][n], 0, 0, 0);
        __syncthreads();                    // drains prefetch vmcnt + LDS reuse fence
        cur ^= 1;
    }

    const float* brow = bias + (bias_ld ? (long)(mb >> 9) * bias_ld : 0);
#pragma unroll
    for (int m = 0; m < 4; ++m) {
        const long grow0 = mb + wr + m * 16 + kl * 4;
#pragma unroll
        for (int n = 0; n < NC; ++n) {
            const long gcol2 = nb + wc + n * 16 + l15;
            const float bb = brow[gcol2];
            f32x4 v = acc[m][n];
#pragma unroll
            for (int r = 0; r < 4; ++r) {
                float x = v[r] + bb;
                if (EPI == 1) x = tanhf(x);
                else if (EPI == 2) x = gelu_ex(x);
                C[(grow0 + r) * (long)ldc + gcol2] = x;
            }
        }
    }
}

// ---------------- fp32 SGEMM (rfft/irfft tables): C[M,N] = A[M,K] * Bt[N,K]^T -------
__global__ __launch_bounds__(256)
void sgemm_bt(const float* __restrict__ A, int lda,
              const float* __restrict__ Bt, int ldb,
              float* __restrict__ C, int ldc, int ktiles)
{
    __shared__ float As[16][68];   // [k][m], 68 = 64 + 4 pad
    __shared__ float Bs[16][68];   // [k][n]
    const int tid = threadIdx.x;
    const int tx = tid & 15, ty = tid >> 4;
    const int lr = tid >> 2, lc = (tid & 3) * 4;     // load: row 0..63, col 4-chunk
    const long mb = (long)blockIdx.x * 64, nb = (long)blockIdx.y * 64;
    float acc[4][4] = {};
    const float* Ap = A  + (mb + lr) * (long)lda + lc;
    const float* Bp = Bt + (nb + lr) * (long)ldb + lc;
    for (int kt = 0; kt < ktiles; ++kt) {
        float4 av = *(const float4*)(Ap + kt * 16);
        float4 bv = *(const float4*)(Bp + kt * 16);
        __syncthreads();
        As[lc + 0][lr] = av.x; As[lc + 1][lr] = av.y;
        As[lc + 2][lr] = av.z; As[lc + 3][lr] = av.w;
        Bs[lc + 0][lr] = bv.x; Bs[lc + 1][lr] = bv.y;
        Bs[lc + 2][lr] = bv.z; Bs[lc + 3][lr] = bv.w;
        __syncthreads();
#pragma unroll
        for (int kk = 0; kk < 16; ++kk) {
            float4 a = *(const float4*)&As[kk][ty * 4];
            float4 b = *(const float4*)&Bs[kk][tx * 4];
            acc[0][0] = fmaf(a.x, b.x, acc[0][0]); acc[0][1] = fmaf(a.x, b.y, acc[0][1]);
            acc[0][2] = fmaf(a.x, b.z, acc[0][2]); acc[0][3] = fmaf(a.x, b.w, acc[0][3]);
            acc[1][0] = fmaf(a.y, b.x, acc[1][0]); acc[1][1] = fmaf(a.y, b.y, acc[1][1]);
            acc[1][2] = fmaf(a.y, b.z, acc[1][2]); acc[1][3] = fmaf(a.y, b.w, acc[1][3]);
            acc[2][0] = fmaf(a.z, b.x, acc[2][0]); acc[2][1] = fmaf(a.z, b.y, acc[2][1]);
            acc[2][2] = fmaf(a.z, b.z, acc[2][2]); acc[2][3] = fmaf(a.z, b.w, acc[2][3]);
            acc[3][0] = fmaf(a.w, b.x, acc[3][0]); acc[3][1] = fmaf(a.w, b.y, acc[3][1]);
            acc[3][2] = fmaf(a.w, b.z, acc[3][2]); acc[3][3] = fmaf(a.w, b.w, acc[3][3]);
        }
    }
#pragma unroll
    for (int i = 0; i < 4; ++i) {
        float4 st = { acc[i][0], acc[i][1], acc[i][2], acc[i][3] };
        *(float4*)&C[(mb + ty * 4 + i) * (long)ldc + nb + tx * 4] = st;
    }
}

// ---------------- setup kernels ----------------
__global__ void build_tables(float* __restrict__ RT, float* __restrict__ IT)
{
    long idx = (long)blockIdx.x * 256 + threadIdx.x;
    const double W = 6.283185307179586476925286766559005768 / 512.0;
    if (idx < 640L * 512) {                  // RT[640][512]: rfft rows (re/im interleaved)
        int r = (int)(idx >> 9), n = (int)(idx & 511);
        float v = 0.f;
        if (r < F2E) {
            int bin = r >> 1;
            int m = (bin * n) & 511;
            double ang = W * m;
            v = (r & 1) ? (float)(-sin(ang)) : (float)cos(ang);
        }
        RT[idx] = v;
    } else {
        long j2 = idx - 640L * 512;          // IT[512][640]: irfft rows
        if (j2 < 512L * 640) {
            int n = (int)(j2 / 640), j = (int)(j2 % 640);
            float v = 0.f;
            if (j < F2E) {
                int bin = j >> 1;
                int m = (bin * n) & 511;
                double ang = W * m;
                bool edge = (bin == 0 || bin == 256);
                double ck = edge ? 1.0 : 2.0;
                if (j & 1) v = edge ? 0.f : (float)(-ck * sin(ang) / 512.0);
                else       v = (float)(ck * cos(ang) / 512.0);
            }
            IT[j2] = v;
        }
    }
}

__global__ void build_damp(float* damp, const float* __restrict__ fd)
{
    int i = blockIdx.x * 256 + threadIdx.x;
    if (i < F2E) damp[i] = fd[i < 257 ? i : i - 257];   // torch repeat(...,2) tiling quirk
}

// split-K ybase partials: Yp[z][b][n] = sum_{k in chunk z} src[b][k]*W1[1028+k][n] + tgt[b][k]*W1[1540+k][n]
__global__ void ybase_part(const float* __restrict__ srcp, const float* __restrict__ tgtp,
                           const float* __restrict__ cw1, const float* __restrict__ tw1,
                           float* __restrict__ Yp)
{
    const int n = blockIdx.x * 256 + threadIdx.x;
    const int b = blockIdx.y, z = blockIdx.z;
    if (n >= NT1) return;
    float acc = 0.f;
    if (n < 2056) {
        const bool isT = (n >= 1028);
        const int nn = isT ? n - 1028 : n;
        const float* w = isT ? tw1 : cw1;
        const float* s = srcp + b * 513;
        const float* t = tgtp + b * 513;
        const int k0 = z * (512 / YZS);
        for (int k = k0; k < k0 + 512 / YZS; ++k) {
            acc = fmaf(s[k], w[(size_t)(1028 + k) * 1028 + nn], acc);
            acc = fmaf(t[k], w[(size_t)(1540 + k) * 1028 + nn], acc);
        }
    }
    Yp[((size_t)z * 8 + b) * NT1 + n] = acc;
}

// Ybase[b][n] = bias1[n] + sum_z Yp[z][b][n]
__global__ void ybase_reduce(const float* __restrict__ Yp,
                             const float* __restrict__ cb1, const float* __restrict__ tb1,
                             float* __restrict__ Yb)
{
    const int n = blockIdx.x * 256 + threadIdx.x;
    const int b = blockIdx.y;
    if (n >= NT1) return;
    float acc = 0.f;
    if (n < 2056) acc = (n < 1028) ? cb1[n] : tb1[n - 1028];
    for (int z = 0; z < YZS; ++z) acc += Yp[((size_t)z * 8 + b) * NT1 + n];
    Yb[b * NT1 + n] = acc;
}

// transpose fp32 [K,N] weights into bf16 [rows=ldn][cols=ldk], zero-padded, 2 segments
__global__ void wprep(bf16* __restrict__ dst, int ldk,
                      const float* s0, int K0, int N0, int r00,
                      const float* s1, int K1, int N1, int r01)
{
    int r = blockIdx.x;
    int k = blockIdx.y * 256 + threadIdx.x;
    if (k >= ldk) return;
    float v = 0.f;
    if (s0 && r >= r00 && r < r00 + N0 && k < K0) v = s0[(long)k * N0 + (r - r00)];
    if (s1 && r >= r01 && r < r01 + N1 && k < K1) v = s1[(long)k * N1 + (r - r01)];
    dst[(long)r * ldk + k] = __float2bfloat16(v);
}

__global__ void bias_fill(float* __restrict__ dst, int n,
                          const float* s0, int l0, int o0,
                          const float* s1, int l1, int o1)
{
    int i = blockIdx.x * 256 + threadIdx.x;
    if (i >= n) return;
    float v = 0.f;
    if (s0 && i >= o0 && i < o0 + l0) v = s0[i - o0];
    if (s1 && i >= o1 && i < o1 + l1) v = s1[i - o1];
    dst[i] = v;
}

__global__ void initconv(const float* __restrict__ cb, const float* __restrict__ tb,
                         bf16* __restrict__ X, bf16* __restrict__ Cb, bf16* __restrict__ Tb)
{
    int row = blockIdx.x;
    for (int j = threadIdx.x; j < F2E; j += 256) {
        float cv = cb[(long)row * CLD + j], tv = tb[(long)row * CLD + j];
        X[(long)row * XCT + j]        = __float2bfloat16(cv);
        X[(long)row * XCT + 514 + j]  = __float2bfloat16(tv);
        Cb[(long)row * KDP + j] = __float2bfloat16(n2n(cv));
        Tb[(long)row * KDP + j] = __float2bfloat16(n2n(tv));
    }
}

// zero the K-pad columns of Xct once (pads never rewritten afterwards)
__global__ void xpad_zero(bf16* __restrict__ X)
{
    int row = blockIdx.x;
    int j = 1028 + threadIdx.x;          // 28 pad cols, 32 threads
    if (j < XCT) X[(long)row * XCT + j] = __float2bfloat16(0.f);
}

// ---------------- per-step kernels (wave-per-row, vectorized) ----------------
__global__ __launch_bounds__(256)
void ln_gelu(const float* __restrict__ Y, bf16* __restrict__ H,
             const float* __restrict__ cg, const float* __restrict__ cbeta,
             const float* __restrict__ tg, const float* __restrict__ tbeta)
{
    const int lane = threadIdx.x & 63, wave = threadIdx.x >> 6;
    const int p = blockIdx.x * 4 + wave;      // 8192 (row,net) pairs
    const int row = p >> 1, net = p & 1;
    const float4* y4 = (const float4*)(Y + (long)row * NT1 + net * 1028);
    float4 v[4], vt = {0.f, 0.f, 0.f, 0.f};
    float s = 0.f;
#pragma unroll
    for (int k = 0; k < 4; ++k) {
        v[k] = y4[lane + k * 64];
        s += v[k].x + v[k].y + v[k].z + v[k].w;
    }
    if (lane == 0) { vt = y4[256]; s += vt.x + vt.y + vt.z + vt.w; }
#pragma unroll
    for (int o = 1; o < 64; o <<= 1) s += __shfl_xor(s, o, 64);
    const float mean = s * (1.0f / 1028.0f);
    float vs = 0.f;
#pragma unroll
    for (int k = 0; k < 4; ++k) {
        float a = v[k].x - mean, b = v[k].y - mean, c = v[k].z - mean, d = v[k].w - mean;
        vs += a * a + b * b + c * c + d * d;
    }
    if (lane == 0) {
        float a = vt.x - mean, b = vt.y - mean, c = vt.z - mean, d = vt.w - mean;
        vs += a * a + b * b + c * c + d * d;
    }
#pragma unroll
    for (int o = 1; o < 64; o <<= 1) vs += __shfl_xor(vs, o, 64);
    const float rs = rsqrtf(vs * (1.0f / 1028.0f) + 1e-5f);
    const float4* g4 = (const float4*)(net ? tg : cg);
    const float4* b4 = (const float4*)(net ? tbeta : cbeta);
    bf16* h = H + (long)row * HLD + (long)net * KH;
#pragma unroll
    for (int k = 0; k < 4; ++k) {
        int j = lane + k * 64;
        float4 gv = g4[j], bv = b4[j];
        ushort4 o;
        o.x = bfb(gelu_ex((v[k].x - mean) * rs * gv.x + bv.x));
        o.y = bfb(gelu_ex((v[k].y - mean) * rs * gv.y + bv.y));
        o.z = bfb(gelu_ex((v[k].z - mean) * rs * gv.z + bv.z));
        o.w = bfb(gelu_ex((v[k].w - mean) * rs * gv.w + bv.w));
        *(ushort4*)(&h[j * 4]) = o;
    }
    if (lane == 0) {
        float4 gv = g4[256], bv = b4[256];
        ushort4 o;
        o.x = bfb(gelu_ex((vt.x - mean) * rs * gv.x + bv.x));
        o.y = bfb(gelu_ex((vt.y - mean) * rs * gv.y + bv.y));
        o.z = bfb(gelu_ex((vt.z - mean) * rs * gv.z + bv.z));
        o.w = bfb(gelu_ex((vt.w - mean) * rs * gv.w + bv.w));
        *(ushort4*)(&h[1024]) = o;
    }
}

// fused heads + state update; per-block partials (NO atomics).
// Hd stacked: rows 0..4095 = c-branch, rows 4096..8191 = t-branch.
// part layout: part[q*1024 + block], q: 0=sum sqrt(dc), 1=sum sqrt(dt), 2=sum nc^2, 3=sum nt^2
__global__ __launch_bounds__(256)
void fused_update(const float* __restrict__ Hd,
                  const float* __restrict__ dw2, const float* __restrict__ db2,
                  const float* __restrict__ sw2, const float* __restrict__ sb2,
                  const float* __restrict__ c, const float* __restrict__ t,
                  const float* __restrict__ fc, const float* __restrict__ ft,
                  float* __restrict__ nc, float* __restrict__ nt,
                  const float* __restrict__ damp,
                  const float* __restrict__ csc, const float* __restrict__ tsc,
                  float* __restrict__ part)
{
    __shared__ float red[16];
    const int tid = threadIdx.x, lane = tid & 63, wave = tid >> 6;
    const int row = blockIdx.x * 4 + wave;

    // --- heads: alpha_c, alpha_t, gamma for this row ---
    const float* hc = Hd + (long)row * NDC;
    const float* ht = Hd + (long)(4096 + row) * NDC;
    float s1 = 0.f, s2 = 0.f, s3 = 0.f;
#pragma unroll
    for (int k = 0; k < 4; ++k) {
        int j = lane + k * 64;
        s1 += hc[j] * dw2[j];
        s3 += ht[j] * dw2[j];
    }
    if (lane == 0) { s1 += hc[256] * dw2[256]; s3 += ht[256] * dw2[256]; }
#pragma unroll
    for (int k = 0; k < 2; ++k) {
        int j = lane + k * 64;
        s2 += hc[257 + j] * sw2[j];
    }
#pragma unroll
    for (int o = 1; o < 64; o <<= 1) {
        s1 += __shfl_xor(s1, o, 64);
        s2 += __shfl_xor(s2, o, 64);
        s3 += __shfl_xor(s3, o, 64);
    }
    float a  = sigm(s1 + db2[0]);
    float at = sigm(s3 + db2[0]);
    float g  = sigm(s2 + sb2[0]) + 0.5f;
    if (isnan(a))  a  = 0.f;
    if (isnan(at)) at = 0.f;
    const float gac = g * a  * csc[0];
    const float gat = g * at * tsc[0];

    // --- damp update + norms (float2, 257 f2 per row) ---
    const float2* c2  = (const float2*)(c  + (long)row * CLD);
    const float2* t2  = (const float2*)(t  + (long)row * CLD);
    const float2* fc2 = (const float2*)(fc + (long)row * CLD);
    const float2* ft2 = (const float2*)(ft + (long)row * CLD);
    float2* nc2 = (float2*)(nc + (long)row * CLD);
    float2* nt2 = (float2*)(nt + (long)row * CLD);
    const float2* d2 = (const float2*)damp;
    float sdc = 0.f, snc = 0.f, sdt = 0.f, snt = 0.f;
#pragma unroll
    for (int k = 0; k < 4; ++k) {
        int j = lane + k * 64;
        float2 dv = d2[j];
        float2 cv = c2[j], fv = fc2[j];
        float2 ncv = { dv.x * cv.x + gac * fv.x, dv.y * cv.y + gac * fv.y };
        nc2[j] = ncv;
        float dx = ncv.x - cv.x, dy = ncv.y - cv.y;
        sdc += dx * dx + dy * dy;
        snc += ncv.x * ncv.x + ncv.y * ncv.y;
        float2 tv = t2[j], gv = ft2[j];
        float2 ntv = { dv.x * tv.x + gat * gv.x, dv.y * tv.y + gat * gv.y };
        nt2[j] = ntv;
        dx = ntv.x - tv.x; dy = ntv.y - tv.y;
        sdt += dx * dx + dy * dy;
        snt += ntv.x * ntv.x + ntv.y * ntv.y;
    }
    if (lane == 0) {    // tail f2 index 256 (elements 512,513)
        float2 dv = d2[256];
        float2 cv = c2[256], fv = fc2[256];
        float2 ncv = { dv.x * cv.x + gac * fv.x, dv.y * cv.y + gac * fv.y };
        nc2[256] = ncv;
        float dx = ncv.x - cv.x, dy = ncv.y - cv.y;
        sdc += dx * dx + dy * dy;
        snc += ncv.x * ncv.x + ncv.y * ncv.y;
        float2 tv = t2[256], gv = ft2[256];
        float2 ntv = { dv.x * tv.x + gat * gv.x, dv.y * tv.y + gat * gv.y };
        nt2[256] = ntv;
        dx = ntv.x - tv.x; dy = ntv.y - tv.y;
        sdt += dx * dx + dy * dy;
        snt += ntv.x * ntv.x + ntv.y * ntv.y;
    }
#pragma unroll
    for (int o = 1; o < 64; o <<= 1) {
        sdc += __shfl_xor(sdc, o, 64);
        snc += __shfl_xor(snc, o, 64);
        sdt += __shfl_xor(sdt, o, 64);
        snt += __shfl_xor(snt, o, 64);
    }
    if (lane == 0) {
        red[wave * 4 + 0] = sqrtf(sdc);
        red[wave * 4 + 1] = sqrtf(sdt);
        red[wave * 4 + 2] = snc;
        red[wave * 4 + 3] = snt;
    }
    __syncthreads();
    if (tid < 4)
        part[tid * 1024 + blockIdx.x] =
            red[0 * 4 + tid] + red[1 * 4 + tid] + red[2 * 4 + tid] + red[3 * 4 + tid];
}

// update3 with fused convergence logic.
// done-flag double-buffered by step: read scal[step], block 0 writes scal[step+1].
__global__ __launch_bounds__(256)
void update3(float* __restrict__ c, float* __restrict__ t,
             const float* __restrict__ nc, const float* __restrict__ nt,
             bf16* __restrict__ X, bf16* __restrict__ Cb, bf16* __restrict__ Tb,
             const float* __restrict__ part, float* __restrict__ scal, int step)
{
    __shared__ float red[4];
    const int tid = threadIdx.x, lane = tid & 63, wave = tid >> 6;
    {
        const float* pq = part + wave * 1024;
        float s = 0.f;
#pragma unroll
        for (int k = 0; k < 16; ++k) s += pq[lane + k * 64];
#pragma unroll
        for (int o = 1; o < 64; o <<= 1) s += __shfl_xor(s, o, 64);
        if (lane == 0) red[wave] = s;
    }
    __syncthreads();
    const float done = scal[step];
    const float dc = red[0] * (1.0f / 4096.0f);
    const float dt = red[1] * (1.0f / 4096.0f);
    const bool conv = (dc < 1e-3f) && (dt < 1e-3f);
    if (blockIdx.x == 0 && tid == 0)
        scal[step + 1] = (done != 0.f || conv) ? 1.f : 0.f;
    if (done != 0.f) return;               // frozen after convergence
    const float nrc = sqrtf(red[2]);
    const float nrt = sqrtf(red[3]);
    const float sc = conv ? 1.f : (nrc > 10.f ? 10.f / nrc : 1.f);
    const float st = conv ? 1.f : (nrt > 10.f ? 10.f / nrt : 1.f);

    const int row = blockIdx.x * 4 + wave;
    const float2* nc2 = (const float2*)(nc + (long)row * CLD);
    const float2* nt2 = (const float2*)(nt + (long)row * CLD);
    float2* c2 = (float2*)(c + (long)row * CLD);
    float2* t2 = (float2*)(t + (long)row * CLD);
    bf16* xr = X  + (long)row * XCT;
    bf16* cb = Cb + (long)row * KDP;
    bf16* tb = Tb + (long)row * KDP;
#pragma unroll
    for (int k = 0; k < 5; ++k) {
        int j = lane + k * 64;
        if (k == 4 && lane > 0) break;      // only f2 idx 256 in tail
        float2 cv = nc2[j]; cv.x *= sc; cv.y *= sc;
        float2 tv = nt2[j]; tv.x *= st; tv.y *= st;
        c2[j] = cv;
        t2[j] = tv;
        *(unsigned*)(xr + j * 2)       = packbf(cv.x, cv.y);
        *(unsigned*)(xr + 514 + j * 2) = packbf(tv.x, tv.y);
        *(unsigned*)(cb + j * 2) = packbf(n2n(cv.x), n2n(cv.y));
        *(unsigned*)(tb + j * 2) = packbf(n2n(tv.x), n2n(tv.y));
    }
}

// ---------------- host ----------------
extern "C" void kernel_launch(void* const* d_in, const int* in_sizes, int n_in,
                              void* d_out, int out_size, void* d_ws, size_t ws_size,
                              hipStream_t stream)
{
    (void)in_sizes; (void)n_in; (void)out_size; (void)ws_size;
    const float* carrier = (const float*)d_in[0];
    const float* traj    = (const float*)d_in[1];
    const float* srcp    = (const float*)d_in[2];
    const float* tgtp    = (const float*)d_in[3];
    const float* cw1 = (const float*)d_in[4];  const float* cb1 = (const float*)d_in[5];
    const float* cg  = (const float*)d_in[6];  const float* cbe = (const float*)d_in[7];
    const float* cw2 = (const float*)d_in[8];  const float* cb2 = (const float*)d_in[9];
    const float* tw1 = (const float*)d_in[10]; const float* tb1 = (const float*)d_in[11];
    const float* tg  = (const float*)d_in[12]; const float* tbe = (const float*)d_in[13];
    const float* tw2 = (const float*)d_in[14]; const float* tb2 = (const float*)d_in[15];
    const float* fd  = (const float*)d_in[16];
    const float* dw1 = (const float*)d_in[17]; const float* db1 = (const float*)d_in[18];
    const float* dw2 = (const float*)d_in[19]; const float* db2 = (const float*)d_in[20];
    const float* sw1 = (const float*)d_in[21]; const float* sb1 = (const float*)d_in[22];
    const float* sw2 = (const float*)d_in[23]; const float* sb2 = (const float*)d_in[24];
    const float* csc = (const float*)d_in[25]; const float* tsc = (const float*)d_in[26];

    char* p = (char*)d_ws;
    size_t off = 0;
    auto take = [&](size_t bytes) { size_t o = off; off += (bytes + 255) & ~(size_t)255; return o; };
    bf16*  Xct  = (bf16*) (p + take((size_t)RTOT * XCT * 2));
    bf16*  W1ct = (bf16*) (p + take((size_t)NT1 * XCT * 2));
    float* Y    = (float*)(p + take((size_t)RTOT * NT1 * 4));
    bf16*  H    = (bf16*) (p + take((size_t)RTOT * HLD * 2));
    bf16*  W2t  = (bf16*) (p + take((size_t)1280 * KH * 2));
    bf16*  Wdc  = (bf16*) (p + take((size_t)NDC * KDP * 2));
    float* Ybase= (float*)(p + take((size_t)8 * NT1 * 4));
    float* Ypart= (float*)(p + take((size_t)YZS * 8 * NT1 * 4));
    float* b2c  = (float*)(p + take(1280 * 4));
    float* bdc  = (float*)(p + take(NDC * 4));
    float* RT   = (float*)(p + take(640L * 512 * 4));
    float* IT   = (float*)(p + take(512L * 640 * 4));
    float* damp = (float*)(p + take(F2E * 4));
    float* cbuf = (float*)(p + take((size_t)RTOT * CLD * 4));
    float* tbuf = (float*)(p + take((size_t)RTOT * CLD * 4));
    float* ncb  = (float*)(p + take((size_t)RTOT * CLD * 4));
    float* ntb  = (float*)(p + take((size_t)RTOT * CLD * 4));
    float* fcb  = (float*)(p + take((size_t)2 * RTOT * CLD * 4)); // [fc | ft] contiguous
    float* ftb  = fcb + (size_t)RTOT * CLD;
    bf16*  Cbb  = (bf16*) (p + take((size_t)2 * RTOT * KDP * 2)); // [Cb | Tb] contiguous
    bf16*  Tbb  = Cbb + (size_t)RTOT * KDP;
    float* Hd   = (float*)(p + take((size_t)2 * RTOT * NDC * 4)); // stacked c|t
    float* part = (float*)(p + take(4096 * 4));
    float* scal = (float*)(p + take(1024));

    hipMemsetAsync(scal, 0, 1024, stream);      // scal[0] = done flag for step 0

    build_tables<<<2560, 256, 0, stream>>>(RT, IT);
    build_damp<<<3, 256, 0, stream>>>(damp, fd);
    ybase_part<<<dim3(9, 8, YZS), 256, 0, stream>>>(srcp, tgtp, cw1, tw1, Ypart);
    ybase_reduce<<<dim3(9, 8), 256, 0, stream>>>(Ypart, cb1, tb1, Ybase);
    wprep<<<dim3(NT1, 5), 256, 0, stream>>>(W1ct, XCT, cw1, 1028, 1028, 0, tw1, 1028, 1028, 1028);
    wprep<<<dim3(1280, 5), 256, 0, stream>>>(W2t, KH, cw2, 1028, 514, 0, tw2, 1028, 514, 640);
    wprep<<<dim3(NDC, 3), 256, 0, stream>>>(Wdc, KDP, dw1, 514, 257, 0, sw1, 514, 128, 257);
    bias_fill<<<5, 256, 0, stream>>>(b2c, 1280, cb2, 514, 0, tb2, 514, 640);
    bias_fill<<<2, 256, 0, stream>>>(bdc, NDC, db1, 257, 0, sb1, 128, 257);
    xpad_zero<<<RTOT, 32, 0, stream>>>(Xct);

    // rfft (fp32 DFT-matmul); RT pad rows also zero the c/t pad columns
    sgemm_bt<<<dim3(64, 10), 256, 0, stream>>>(carrier, SP, RT, SP, cbuf, CLD, 32);
    sgemm_bt<<<dim3(64, 10), 256, 0, stream>>>(traj,    SP, RT, SP, tbuf, CLD, 32);
    initconv<<<RTOT, 256, 0, stream>>>(cbuf, tbuf, Xct, Cbb, Tbb);

    for (int s = 0; s < 20; ++s) {
        // GEMM1: [c,t] x W1ct^T + Ybase[batch]  (packed N=2176, BN=128, dbuf)
        gemm_bt<0, 128><<<dim3(32, 17), 256, 0, stream>>>(Xct, XCT, W1ct, XCT, Y, NT1,
                                                          Ybase, NT1, 33, 0, 0, 0, 0);
        ln_gelu<<<2048, 256, 0, stream>>>(Y, H, cg, cbe, tg, tbe);
        // GEMM2 (both nets via z; BN=64 -> 640 blocks for occupancy)
        gemm_bt<1, 64><<<dim3(32, 10, 2), 256, 0, stream>>>(H, HLD, W2t, KH, fcb, CLD,
                                                            b2c, 0, 34,
                                                            (long)KH, (long)640 * KH,
                                                            (long)RTOT * CLD, 640);
        // small-MLP hidden, stacked c|t (M=8192); BN=64 -> 512 blocks
        gemm_bt<2, 64><<<dim3(64, 8), 256, 0, stream>>>(Cbb, KDP, Wdc, KDP, Hd, NDC,
                                                        bdc, 0, 18, 0, 0, 0, 0);
        fused_update<<<1024, 256, 0, stream>>>(Hd, dw2, db2, sw2, sb2,
                                               cbuf, tbuf, fcb, ftb, ncb, ntb,
                                               damp, csc, tsc, part);
        update3<<<1024, 256, 0, stream>>>(cbuf, tbuf, ncb, ntb, Xct, Cbb, Tbb,
                                          part, scal, s);
    }

    float* out = (float*)d_out;
    sgemm_bt<<<dim3(64, 8), 256, 0, stream>>>(cbuf, CLD, IT, CLD, out, SP, 40);
    sgemm_bt<<<dim3(64, 8), 256, 0, stream>>>(tbuf, CLD, IT, CLD, out + (size_t)RTOT * SP, SP, 40);
}